// Round 13
// baseline (327.588 us; speedup 1.0000x reference)
//
#include <hip/hip_runtime.h>

#define B_   4
#define C_   512
#define S_   4096
#define G_   32
#define CPG_ 16
#define EPS_ 1e-6f

typedef unsigned short u16;
typedef __bf16 bf16x8 __attribute__((ext_vector_type(8)));
typedef float  f32x4  __attribute__((ext_vector_type(4)));
typedef float  f32x16 __attribute__((ext_vector_type(16)));

__device__ __forceinline__ u16 f2bf(float f) {
  unsigned u = __float_as_uint(f);
  u += 0x7fffu + ((u >> 16) & 1u);   // RNE
  return (u16)(u >> 16);
}
__device__ __forceinline__ float bf2f(u16 h) {
  return __uint_as_float((unsigned)h << 16);
}

__device__ __forceinline__ void g2lds16(const void* g, void* l) {
  __builtin_amdgcn_global_load_lds(
      (const __attribute__((address_space(1))) void*)g,
      (__attribute__((address_space(3))) void*)l, 16, 0, 0);
}

#define BAR()    __builtin_amdgcn_s_barrier()
#define SCHED0() __builtin_amdgcn_sched_barrier(0)
#define WAITV4   asm volatile("s_waitcnt vmcnt(4)" ::: "memory")
#define WAITV0   asm volatile("s_waitcnt vmcnt(0)" ::: "memory")

// chunked XCD swizzle (bijective when nwg % 8 == 0 — all grids here satisfy it)
__device__ __forceinline__ void xcd_swz(int& bx, int& by, int& bz) {
  const int gx = gridDim.x, gy = gridDim.y;
  const int nwg = gx * gy * (int)gridDim.z;
  const int flat = blockIdx.x + gx * (blockIdx.y + gy * blockIdx.z);
  const int q = nwg >> 3;
  const int nf = (flat & 7) * q + (flat >> 3);
  bx = nf % gx;
  const int r = nf / gx;
  by = r % gy;
  bz = r / gy;
}

// ---------------- fp32 -> bf16 weight conversion ----------------
__global__ __launch_bounds__(256) void f32_to_bf16(const float* __restrict__ in,
                                                   u16* __restrict__ out, int n) {
  int i = blockIdx.x * 256 + threadIdx.x;
  if (i < n) out[i] = f2bf(in[i]);
}

__global__ __launch_bounds__(256) void concat_bias(const float* __restrict__ a,
                                                   const float* __restrict__ b,
                                                   float* __restrict__ o) {
  int i = blockIdx.x * 256 + threadIdx.x;  // grid 4 -> 1024
  o[i] = (i < 512) ? a[i] : b[i - 512];
}

// ---------------- softmax denominator: Lr[b,i] = 1/sum_jb partial ----------------
__global__ __launch_bounds__(256) void reduce_l(const float* __restrict__ p,
                                                float* __restrict__ lr) {
  const int i = blockIdx.x * 256 + threadIdx.x;   // 16384 = B*S
  const int b = i >> 12, row = i & 4095;
  float s = 0.f;
#pragma unroll
  for (int jb = 0; jb < 16; ++jb) s += p[((size_t)(b * 16 + jb) << 12) + row];
  lr[i] = 1.f / s;
}

// ---------------- GroupNorm stats: one block per (b,g) ----------------
__global__ __launch_bounds__(256) void gn_stats(const float* __restrict__ x,
                                                float* __restrict__ stats) {
  const int bg = blockIdx.x;
  const float4* p4 = (const float4*)(x + (size_t)bg * (CPG_ * S_));
  float s = 0.f, ss = 0.f;
  const int tid = threadIdx.x;
  for (int i = tid; i < CPG_ * S_ / 4; i += 256) {
    float4 v = p4[i];
    s  += v.x + v.y + v.z + v.w;
    ss += v.x * v.x + v.y * v.y + v.z * v.z + v.w * v.w;
  }
#pragma unroll
  for (int o = 32; o; o >>= 1) { s += __shfl_xor(s, o, 64); ss += __shfl_xor(ss, o, 64); }
  __shared__ float sm[8];
  const int wid = tid >> 6, lane = tid & 63;
  if (lane == 0) { sm[wid * 2] = s; sm[wid * 2 + 1] = ss; }
  __syncthreads();
  if (tid == 0) {
    s  = sm[0] + sm[2] + sm[4] + sm[6];
    ss = sm[1] + sm[3] + sm[5] + sm[7];
    const float inv = 1.f / (float)(CPG_ * S_);
    float mu = s * inv;
    float var = ss * inv - mu * mu;
    stats[bg * 2]     = mu;
    stats[bg * 2 + 1] = rsqrtf(var + EPS_);
  }
}

// ---------------- normalize + transpose: x[b,c,s] -> ht[b*s, c] bf16 ----------------
__global__ __launch_bounds__(256) void gn_apply_t(const float* __restrict__ x,
                                                  const float* __restrict__ gamma,
                                                  const float* __restrict__ beta,
                                                  const float* __restrict__ stats,
                                                  u16* __restrict__ ht) {
  __shared__ float tile[32][33];
  const int b = blockIdx.z, c0 = blockIdx.y * 32, s0 = blockIdx.x * 32;
  const int tx = threadIdx.x, ty = threadIdx.y;
#pragma unroll
  for (int i = 0; i < 4; ++i) {
    const int c  = c0 + ty + i * 8;
    const float mu = stats[(b * G_ + (c >> 4)) * 2];
    const float rs = stats[(b * G_ + (c >> 4)) * 2 + 1];
    const float v  = x[((size_t)b * C_ + c) * S_ + s0 + tx];
    tile[ty + i * 8][tx] = (v - mu) * rs * gamma[c] + beta[c];
  }
  __syncthreads();
#pragma unroll
  for (int i = 0; i < 4; ++i) {
    const int s = s0 + ty + i * 8;
    ht[((size_t)b * S_ + s) * C_ + c0 + tx] = f2bf(tile[tx][ty + i * 8]);
  }
}

// ======= 256x256 8-phase GEMM — 32x32x16 MFMA, single barrier/phase =======
// C[m,n] = alpha * sum_k A[m,k]*B[n,k] (+bias[n]); A,B bf16 K-contiguous.
// 512 thr = 8 waves (2M gm x 4N gn). Per-wave output: rows {AH*128+gm*64 ..+63},
// cols {BH*128+gn*32 ..+31} over AH,BH in {0,1} -> 128x64.
// Fragments: 32x32x16 bf16. A-frag: lane holds A[row=base+(lane&31)]
// [k=(lane>>5)*8 ..+7] (natural K-extension of the verified 16x16x32 mapping).
// C/D: col=lane&31, row=(reg&3)+8*(reg>>2)+4*(lane>>5)  [HW-verified m74/m101].
// LDS As/Bs[2 dbuf][2 half][128 rows][64 K] u16; swizzle phys granule = g^(row&7)
// both sides. Phase = one (AH,BH) C-quadrant x K=64: 8 MFMA, 2 indep chains.
// Reads: RDA32 8xb128 per A-half (p0/p2), RDB32 4xb128 per B-half (p0/p1);
// b0_ stays live through p3. Stage/drain ledger identical to R12 (counted
// vmcnt(4) at p3/p7 pre-barrier; steady 12 in flight, never 0).
// ZMODE 1 = PV split-K: bz -> (b = bz>>1, kh = bz&1), hardcoded offsets.
// SMAX 1 = scores epilogue: write exp(alpha*acc) bf16 + per-block row-sum partials.
template <int BIAS_MODE, int ZMODE, int SMAX>
__global__ __launch_bounds__(512, 2) void gemm8p(
    const u16* __restrict__ Ag, int lda, long sA,
    const u16* __restrict__ Bg, int ldb, long sB,
    u16* __restrict__ Cg, int ldc, long sC,
    const float* __restrict__ bias, float alpha, int K,
    float* __restrict__ smx) {
  __shared__ u16 As[2][2][8192];
  __shared__ u16 Bs[2][2][8192];
  __shared__ float ps[4][256];
  int bx, by, bz;
  xcd_swz(bx, by, bz);
  const u16 *A, *Bm;
  u16* Cb;
  if (ZMODE == 0) {
    A = Ag + (size_t)bz * sA; Bm = Bg + (size_t)bz * sB; Cb = Cg + (size_t)bz * sC;
  } else {  // PV split-K: A = P[b], cols kh*2048+; B = V rows, cols b*4096+kh*2048+
    const int b = bz >> 1, kh = bz & 1;
    A  = Ag + (size_t)b * 16777216 + (size_t)kh * 2048;
    Bm = Bg + (size_t)b * 4096 + (size_t)kh * 2048;
    Cb = Cg + (size_t)kh * 8388608 + (size_t)b * 2097152;
  }
  const int bm = by * 256, bn = bx * 256;
  const int tid = threadIdx.x;
  const int wid = tid >> 6, lane = tid & 63;
  const int gm = wid >> 2, gn = wid & 3;
  const int l31 = lane & 31, h5 = lane >> 5;

  // half-local fragment read rows
  const int rowA0 = gm * 64 + l31;   // A frag f=0
  const int rowA1 = rowA0 + 32;      // A frag f=1
  const int rowB  = gn * 32 + l31;   // B frag

  // staging: wave w covers rows w*8..w*8+7 (+64) of each half; pre-swizzled source
  const int sg = (lane & 7) ^ ((lane >> 3) & 7);
  const u16* Abase = A  + (size_t)(bm + wid * 8 + (lane >> 3)) * lda + sg * 8;
  const u16* Bbase = Bm + (size_t)(bn + wid * 8 + (lane >> 3)) * ldb + sg * 8;

#define STGA(D, H, T) do {                                                   \
    const u16* _s = Abase + (size_t)((H) * 128) * lda + (size_t)(T) * 64;    \
    g2lds16(_s,                    &As[D][H][wid * 512]);                    \
    g2lds16(_s + (size_t)64 * lda, &As[D][H][4096 + wid * 512]);             \
  } while (0)
#define STGB(D, H, T) do {                                                   \
    const u16* _s = Bbase + (size_t)((H) * 128) * ldb + (size_t)(T) * 64;    \
    g2lds16(_s,                    &Bs[D][H][wid * 512]);                    \
    g2lds16(_s + (size_t)64 * ldb, &Bs[D][H][4096 + wid * 512]);             \
  } while (0)

  // bias preload FIRST: drained by the prologue vmcnt(4)
  float bias_v[2] = {0.f, 0.f};
  if (BIAS_MODE == 1) {
#pragma unroll
    for (int bh = 0; bh < 2; ++bh) bias_v[bh] = bias[bn + bh * 128 + gn * 32 + l31];
  }
  SCHED0();

  f32x16 acc[4][2];  // [AH*2+f][BH]
  const f32x16 zero16 = {0.f, 0.f, 0.f, 0.f, 0.f, 0.f, 0.f, 0.f,
                         0.f, 0.f, 0.f, 0.f, 0.f, 0.f, 0.f, 0.f};
#pragma unroll
  for (int i = 0; i < 4; ++i)
#pragma unroll
    for (int j = 0; j < 2; ++j) acc[i][j] = zero16;

  bf16x8 a_[2][4], b0_[4], b1_[4];

#define RDA32(D, AH) do {                                                    \
    _Pragma("unroll") for (int ks = 0; ks < 4; ++ks) {                       \
      const int g = ks * 2 + h5;                                             \
      a_[0][ks] = *(const bf16x8*)&As[D][AH][rowA0 * 64 + ((g ^ (rowA0 & 7)) << 3)]; \
      a_[1][ks] = *(const bf16x8*)&As[D][AH][rowA1 * 64 + ((g ^ (rowA1 & 7)) << 3)]; \
    } } while (0)
#define RDB32(D, BH, BREG) do {                                              \
    _Pragma("unroll") for (int ks = 0; ks < 4; ++ks) {                       \
      const int g = ks * 2 + h5;                                             \
      BREG[ks] = *(const bf16x8*)&Bs[D][BH][rowB * 64 + ((g ^ (rowB & 7)) << 3)]; \
    } } while (0)
#define MM32(AH, BH, BREG) do {                                              \
    __builtin_amdgcn_s_setprio(1);                                           \
    _Pragma("unroll") for (int ks = 0; ks < 4; ++ks) {                       \
      acc[(AH) * 2 + 0][BH] = __builtin_amdgcn_mfma_f32_32x32x16_bf16(       \
          a_[0][ks], BREG[ks], acc[(AH) * 2 + 0][BH], 0, 0, 0);              \
      acc[(AH) * 2 + 1][BH] = __builtin_amdgcn_mfma_f32_32x32x16_bf16(       \
          a_[1][ks], BREG[ks], acc[(AH) * 2 + 1][BH], 0, 0, 0);              \
    }                                                                        \
    __builtin_amdgcn_s_setprio(0);                                           \
  } while (0)

  // prologue: tile0 all 4 halves, then tile1 A0,B1; drain tile0 BEFORE the barrier
  STGA(0, 0, 0); STGB(0, 1, 0); STGA(0, 1, 0); STGB(0, 0, 0);
  STGA(1, 0, 1); STGB(1, 1, 1);
  WAITV4;
  BAR();

  const int nt = K >> 6;  // even, >= 4
  for (int i = 0; i < nt / 2; ++i) {
    const int t1 = 2 * i + 1, t2 = 2 * i + 2, t3 = 2 * i + 3;
    const bool s2 = t2 < nt, s3 = t3 < nt;
    // p0 (d0, A0,B0)
    RDA32(0, 0); RDB32(0, 0, b0_);
    STGB(1, 0, t1);
    BAR(); MM32(0, 0, b0_);
    // p1 (d0, A0,B1)
    RDB32(0, 1, b1_);
    STGA(1, 1, t1);
    BAR(); MM32(0, 1, b1_);
    // p2 (d0, A1,B1)
    RDA32(0, 1);
    if (s2) STGA(0, 0, t2);
    BAR(); MM32(1, 1, b1_);
    // p3 (d0, A1,B0) — counted drain of d1's stages before the phase barrier
    if (s2) STGB(0, 1, t2);
    if (s2) { WAITV4; } else { WAITV0; }
    BAR(); MM32(1, 0, b0_);
    // p4 (d1, A0,B0)
    RDA32(1, 0); RDB32(1, 0, b0_);
    if (s2) STGA(0, 1, t2);
    BAR(); MM32(0, 0, b0_);
    // p5 (d1, A0,B1)
    RDB32(1, 1, b1_);
    if (s2) STGB(0, 0, t2);
    BAR(); MM32(0, 1, b1_);
    // p6 (d1, A1,B1)
    RDA32(1, 1);
    if (s3) STGA(1, 0, t3);
    BAR(); MM32(1, 1, b1_);
    // p7 (d1, A1,B0) — counted drain of next d0's stages before the phase barrier
    if (s3) STGB(1, 1, t3);
    if (s3) { WAITV4; }
    BAR(); MM32(1, 0, b0_);
  }
#undef STGA
#undef STGB
#undef RDA32
#undef RDB32
#undef MM32
  SCHED0();

  // epilogue: C/D mapping col = lane&31, row = (reg&3)+8*(reg>>2)+4*h5
  if (SMAX) {
#pragma unroll
    for (int AH = 0; AH < 2; ++AH)
#pragma unroll
      for (int f = 0; f < 2; ++f) {
        float rsl[16];
#pragma unroll
        for (int r = 0; r < 16; ++r) rsl[r] = 0.f;
        const int rowbase = bm + AH * 128 + gm * 64 + f * 32;
#pragma unroll
        for (int BH = 0; BH < 2; ++BH) {
          const int colg = bn + BH * 128 + gn * 32 + l31;
#pragma unroll
          for (int r = 0; r < 16; ++r) {
            const int rowg = rowbase + (r & 3) + 8 * (r >> 2) + 4 * h5;
            const float e = __expf(acc[AH * 2 + f][BH][r] * alpha);
            rsl[r] += e;
            Cb[(size_t)rowg * ldc + colg] = f2bf(e);
          }
        }
        // sum over this wave's 32 cols (within each 32-lane half = same row set)
#pragma unroll
        for (int r = 0; r < 16; ++r) {
          float v = rsl[r];
          v += __shfl_xor(v, 1, 64);
          v += __shfl_xor(v, 2, 64);
          v += __shfl_xor(v, 4, 64);
          v += __shfl_xor(v, 8, 64);
          v += __shfl_xor(v, 16, 64);
          const int rr = (r & 3) + 8 * (r >> 2) + 4 * h5;
          if (l31 == rr)
            ps[gn][AH * 128 + gm * 64 + f * 32 + rr] = v;
        }
      }
    __syncthreads();
    if (tid < 256) {
      const float tot = ps[0][tid] + ps[1][tid] + ps[2][tid] + ps[3][tid];
      smx[((size_t)(bz * 16 + bx) << 12) + bm + tid] = tot;
    }
  } else {
#pragma unroll
    for (int AH = 0; AH < 2; ++AH)
#pragma unroll
      for (int f = 0; f < 2; ++f) {
        const int rowbase = bm + AH * 128 + gm * 64 + f * 32;
#pragma unroll
        for (int BH = 0; BH < 2; ++BH) {
          const int colg = bn + BH * 128 + gn * 32 + l31;
#pragma unroll
          for (int r = 0; r < 16; ++r) {
            const int rowg = rowbase + (r & 3) + 8 * (r >> 2) + 4 * h5;
            Cb[(size_t)rowg * ldc + colg] =
                f2bf(acc[AH * 2 + f][BH][r] * alpha + bias_v[BH]);
          }
        }
      }
  }
}

// ---------------- 128x128 GEMM (V-proj and out-proj) ----------------
// BCOMB=1: B-operand is the fp32 sum of two bf16 psum buffers (Bg, Bg2), added
// during reg-staged B-staging (replaces the separate add_scale pass).
// OUT_MODE=1: fp32 out[b,o,s] = acc*lscale[n] + bias[m] + xres, n = b*S+s.
#define GBM 128
#define GBN 128
#define GBK 64

template <int BIAS_MODE, int OUT_MODE, int BCOMB>
__global__ __launch_bounds__(256) void gemm_abT(
    const u16* __restrict__ Ag, int lda, long sA,
    const u16* __restrict__ Bg, int ldb, long sB,
    void* __restrict__ Cg, int ldc, long sC,
    const float* __restrict__ bias, float alpha,
    const float* __restrict__ xres, const float* __restrict__ lscale,
    const u16* __restrict__ Bg2, int K) {
  __shared__ u16 As[GBM * GBK];
  __shared__ u16 Bs[GBN * GBK];
  const int bz = blockIdx.z;
  const u16* A    = Ag + (size_t)bz * sA;
  const u16* Bmat = Bg + (size_t)bz * sB;
  const int bm = blockIdx.y * GBM, bn = blockIdx.x * GBN;
  const int tid = threadIdx.x;
  const int wid = tid >> 6, lane = tid & 63;
  const int wm = (wid >> 1) * 64, wn = (wid & 1) * 64;
  const int lr = lane & 15, lh = lane >> 4;
  const int srow = lane >> 3, scol = (lane & 7) * 8;

  f32x4 acc[4][4];
  const f32x4 zero = {0.f, 0.f, 0.f, 0.f};
#pragma unroll
  for (int i = 0; i < 4; ++i)
#pragma unroll
    for (int j = 0; j < 4; ++j) acc[i][j] = zero;

  for (int k0 = 0; k0 < K; k0 += GBK) {
    __syncthreads();
#pragma unroll
    for (int i = 0; i < 4; ++i) {
      const int chunk = wid * 4 + i;
      const int row   = chunk * 8 + srow;
      g2lds16(A + (size_t)(bm + row) * lda + (k0 + scol), &As[chunk * 512]);
      if (BCOMB == 0) {
        g2lds16(Bmat + (size_t)(bn + row) * ldb + (k0 + scol), &Bs[chunk * 512]);
      } else {
        const size_t boff = (size_t)(bn + row) * ldb + (k0 + scol);
        const uint4 u0 = *(const uint4*)(Bmat + boff);
        const uint4 u1 = *(const uint4*)(Bg2 + boff);
        const unsigned* p0 = (const unsigned*)&u0;
        const unsigned* p1 = (const unsigned*)&u1;
        unsigned rr[4];
#pragma unroll
        for (int k = 0; k < 4; ++k) {
          const float lo = bf2f((u16)(p0[k] & 0xffffu)) + bf2f((u16)(p1[k] & 0xffffu));
          const float hi = bf2f((u16)(p0[k] >> 16)) + bf2f((u16)(p1[k] >> 16));
          rr[k] = (unsigned)f2bf(lo) | ((unsigned)f2bf(hi) << 16);
        }
        *(uint4*)&Bs[chunk * 512 + lane * 8] = *(const uint4*)rr;
      }
    }
    __syncthreads();
#pragma unroll
    for (int ks = 0; ks < 2; ++ks) {
      bf16x8 a_[4], b_[4];
#pragma unroll
      for (int m = 0; m < 4; ++m)
        a_[m] = *(const bf16x8*)&As[(wm + m * 16 + lr) * GBK + ks * 32 + lh * 8];
#pragma unroll
      for (int n = 0; n < 4; ++n)
        b_[n] = *(const bf16x8*)&Bs[(wn + n * 16 + lr) * GBK + ks * 32 + lh * 8];
#pragma unroll
      for (int m = 0; m < 4; ++m)
#pragma unroll
        for (int n = 0; n < 4; ++n)
          acc[m][n] = __builtin_amdgcn_mfma_f32_16x16x32_bf16(a_[m], b_[n], acc[m][n], 0, 0, 0);
    }
  }

  if (OUT_MODE == 0) {
    u16* Cb = (u16*)Cg + (size_t)bz * sC;
#pragma unroll
    for (int m = 0; m < 4; ++m) {
      const int row0 = bm + wm + m * 16 + lh * 4;
#pragma unroll
      for (int n = 0; n < 4; ++n) {
        const int col = bn + wn + n * 16 + lr;
        float bn_ = (BIAS_MODE == 1) ? bias[col] : 0.f;
#pragma unroll
        for (int r = 0; r < 4; ++r) {
          float bb = (BIAS_MODE == 2) ? bias[row0 + r] : bn_;
          Cb[(size_t)(row0 + r) * ldc + col] = f2bf(acc[m][n][r] * alpha + bb);
        }
      }
    }
  } else {
    float* Ob = (float*)Cg;
#pragma unroll
    for (int m = 0; m < 4; ++m) {
      const int row0 = bm + wm + m * 16 + lh * 4;
#pragma unroll
      for (int n = 0; n < 4; ++n) {
        const int col = bn + wn + n * 16 + lr;
        const int bb = col >> 12, sp = col & (S_ - 1);
        const float lsc = lscale[col];
#pragma unroll
        for (int r = 0; r < 4; ++r) {
          const int o = row0 + r;
          const size_t idx = ((size_t)bb * C_ + o) * S_ + sp;
          Ob[idx] = acc[m][n][r] * lsc + bias[o] + xres[idx];
        }
      }
    }
  }
}

extern "C" void kernel_launch(void* const* d_in, const int* in_sizes, int n_in,
                              void* d_out, int out_size, void* d_ws, size_t ws_size,
                              hipStream_t stream) {
  const float* x     = (const float*)d_in[0];
  const float* gamma = (const float*)d_in[1];
  const float* beta  = (const float*)d_in[2];
  const float* wq = (const float*)d_in[3];
  const float* bq = (const float*)d_in[4];
  const float* wk = (const float*)d_in[5];
  const float* bk = (const float*)d_in[6];
  const float* wv = (const float*)d_in[7];
  const float* bv = (const float*)d_in[8];
  const float* wo = (const float*)d_in[9];
  const float* bo = (const float*)d_in[10];
  float* out = (float*)d_out;

  // ws: stats 1KB | weights bf16 4x512KB | bqk 4KB | ht 16MB | qkt 32MB | vv 16MB
  //     | sc 128MB | partials 1MB | Lr 64KB
  char* ws = (char*)d_ws;
  float* stats = (float*)ws;
  u16* wqb = (u16*)(ws + 1024);
  u16* wkb = wqb + 262144;   // contiguous after wqb -> [wq;wk] is one 1024x512 matrix
  u16* wvb = wkb + 262144;
  u16* wob = wvb + 262144;
  float* bqk = (float*)(wob + 262144);
  u16* ht  = (u16*)((char*)bqk + 4096);  // [B*S, C]
  u16* qkt = ht + 8388608;               // [B*S, 1024] (q|k); later PV psum halves
  u16* vv  = qkt + 16777216;             // [C, B*S]
  u16* sc  = vv + 8388608;               // [B, S, S] exp(scores)
  float* partials = (float*)(sc + 67108864);  // [B][16][4096]
  float* Lr = partials + 262144;              // [B][4096]

  f32_to_bf16<<<1024, 256, 0, stream>>>(wq, wqb, 262144);
  f32_to_bf16<<<1024, 256, 0, stream>>>(wk, wkb, 262144);
  f32_to_bf16<<<1024, 256, 0, stream>>>(wv, wvb, 262144);
  f32_to_bf16<<<1024, 256, 0, stream>>>(wo, wob, 262144);
  concat_bias<<<4, 256, 0, stream>>>(bq, bk, bqk);

  gn_stats<<<128, 256, 0, stream>>>(x, stats);
  gn_apply_t<<<dim3(128, 16, 4), dim3(32, 8), 0, stream>>>(x, gamma, beta, stats, ht);

  // fused Q|K projection: qkt[bs, 0:512]=Q, [512:1024]=K   (256 blocks)
  gemm8p<1, 0, 0><<<dim3(4, 64, 1), 512, 0, stream>>>(ht, 512, 0, wqb, 512, 0,
                                                      qkt, 1024, 0, bqk, 1.f, 512, nullptr);
  // V[c, b*S+s]: bias per m (=c)                            (512 blocks)
  gemm_abT<2, 0, 0><<<dim3(128, 4, 1), 256, 0, stream>>>(wvb, 512, 0, ht, 512, 0,
                                                         vv, 16384, 0, bv, 1.f,
                                                         nullptr, nullptr, nullptr, 512);
  // P[b,i,j] = exp(scale * Q.K) + row-sum partials          (1024 blocks)
  gemm8p<0, 0, 1><<<dim3(16, 16, 4), 512, 0, stream>>>(qkt, 1024, 4194304, qkt + 512, 1024, 4194304,
                                                       sc, 4096, 16777216, nullptr,
                                                       0.04419417382415922f, 512, partials);
  reduce_l<<<64, 256, 0, stream>>>(partials, Lr);
  // PV split-K=2 on unnormalized P: psums in qkt halves     (256 blocks)
  gemm8p<0, 1, 0><<<dim3(2, 16, 8), 512, 0, stream>>>(sc, 4096, 0, vv, 16384, 0,
                                                      qkt, 512, 0, nullptr, 1.f, 2048, nullptr);
  // out[b,o,s] = (Wo @ (psum0+psum1)) * Lr[bs] + bo + x      (512 blocks)
  gemm_abT<2, 1, 1><<<dim3(128, 4, 1), 256, 0, stream>>>(wob, 512, 0, qkt, 512, 0,
                                                         out, 0, 0, bo, 1.f,
                                                         x, Lr, qkt + 8388608, 512);
}

// Round 14
// 296.158 us; speedup vs baseline: 1.1061x; 1.1061x over previous
//
#include <hip/hip_runtime.h>

#define B_   4
#define C_   512
#define S_   4096
#define G_   32
#define CPG_ 16
#define EPS_ 1e-6f

typedef unsigned short u16;
typedef __bf16 bf16x8 __attribute__((ext_vector_type(8)));
typedef float  f32x4  __attribute__((ext_vector_type(4)));

__device__ __forceinline__ u16 f2bf(float f) {
  unsigned u = __float_as_uint(f);
  u += 0x7fffu + ((u >> 16) & 1u);   // RNE
  return (u16)(u >> 16);
}
__device__ __forceinline__ float bf2f(u16 h) {
  return __uint_as_float((unsigned)h << 16);
}

__device__ __forceinline__ void g2lds16(const void* g, void* l) {
  __builtin_amdgcn_global_load_lds(
      (const __attribute__((address_space(1))) void*)g,
      (__attribute__((address_space(3))) void*)l, 16, 0, 0);
}

#define BAR()    __builtin_amdgcn_s_barrier()
#define SCHED0() __builtin_amdgcn_sched_barrier(0)
#define WAITV4   asm volatile("s_waitcnt vmcnt(4)" ::: "memory")
#define WAITV0   asm volatile("s_waitcnt vmcnt(0)" ::: "memory")

// chunked XCD swizzle (bijective when nwg % 8 == 0 — all grids here satisfy it)
__device__ __forceinline__ void xcd_swz(int& bx, int& by, int& bz) {
  const int gx = gridDim.x, gy = gridDim.y;
  const int nwg = gx * gy * (int)gridDim.z;
  const int flat = blockIdx.x + gx * (blockIdx.y + gy * blockIdx.z);
  const int q = nwg >> 3;
  const int nf = (flat & 7) * q + (flat >> 3);
  bx = nf % gx;
  const int r = nf / gx;
  by = r % gy;
  bz = r / gy;
}

// ---------------- fp32 -> bf16 weight conversion ----------------
__global__ __launch_bounds__(256) void f32_to_bf16(const float* __restrict__ in,
                                                   u16* __restrict__ out, int n) {
  int i = blockIdx.x * 256 + threadIdx.x;
  if (i < n) out[i] = f2bf(in[i]);
}

__global__ __launch_bounds__(256) void concat_bias(const float* __restrict__ a,
                                                   const float* __restrict__ b,
                                                   float* __restrict__ o) {
  int i = blockIdx.x * 256 + threadIdx.x;  // grid 4 -> 1024
  o[i] = (i < 512) ? a[i] : b[i - 512];
}

// ---------------- softmax denominator: Lr[b,i] = 1/sum_jb partial ----------------
__global__ __launch_bounds__(256) void reduce_l(const float* __restrict__ p,
                                                float* __restrict__ lr) {
  const int i = blockIdx.x * 256 + threadIdx.x;   // 16384 = B*S
  const int b = i >> 12, row = i & 4095;
  float s = 0.f;
#pragma unroll
  for (int jb = 0; jb < 16; ++jb) s += p[((size_t)(b * 16 + jb) << 12) + row];
  lr[i] = 1.f / s;
}

// ---------------- GroupNorm stats: one block per (b,g) ----------------
__global__ __launch_bounds__(256) void gn_stats(const float* __restrict__ x,
                                                float* __restrict__ stats) {
  const int bg = blockIdx.x;
  const float4* p4 = (const float4*)(x + (size_t)bg * (CPG_ * S_));
  float s = 0.f, ss = 0.f;
  const int tid = threadIdx.x;
  for (int i = tid; i < CPG_ * S_ / 4; i += 256) {
    float4 v = p4[i];
    s  += v.x + v.y + v.z + v.w;
    ss += v.x * v.x + v.y * v.y + v.z * v.z + v.w * v.w;
  }
#pragma unroll
  for (int o = 32; o; o >>= 1) { s += __shfl_xor(s, o, 64); ss += __shfl_xor(ss, o, 64); }
  __shared__ float sm[8];
  const int wid = tid >> 6, lane = tid & 63;
  if (lane == 0) { sm[wid * 2] = s; sm[wid * 2 + 1] = ss; }
  __syncthreads();
  if (tid == 0) {
    s  = sm[0] + sm[2] + sm[4] + sm[6];
    ss = sm[1] + sm[3] + sm[5] + sm[7];
    const float inv = 1.f / (float)(CPG_ * S_);
    float mu = s * inv;
    float var = ss * inv - mu * mu;
    stats[bg * 2]     = mu;
    stats[bg * 2 + 1] = rsqrtf(var + EPS_);
  }
}

// ---------------- normalize + transpose: x[b,c,s] -> ht[b*s, c] bf16 ----------------
__global__ __launch_bounds__(256) void gn_apply_t(const float* __restrict__ x,
                                                  const float* __restrict__ gamma,
                                                  const float* __restrict__ beta,
                                                  const float* __restrict__ stats,
                                                  u16* __restrict__ ht) {
  __shared__ float tile[32][33];
  const int b = blockIdx.z, c0 = blockIdx.y * 32, s0 = blockIdx.x * 32;
  const int tx = threadIdx.x, ty = threadIdx.y;
#pragma unroll
  for (int i = 0; i < 4; ++i) {
    const int c  = c0 + ty + i * 8;
    const float mu = stats[(b * G_ + (c >> 4)) * 2];
    const float rs = stats[(b * G_ + (c >> 4)) * 2 + 1];
    const float v  = x[((size_t)b * C_ + c) * S_ + s0 + tx];
    tile[ty + i * 8][tx] = (v - mu) * rs * gamma[c] + beta[c];
  }
  __syncthreads();
#pragma unroll
  for (int i = 0; i < 4; ++i) {
    const int s = s0 + ty + i * 8;
    ht[((size_t)b * S_ + s) * C_ + c0 + tx] = f2bf(tile[tx][ty + i * 8]);
  }
}

// ======= 256x256 8-phase GEMM — R12 exact (16x16x32, single barrier/phase) =======
// C[m,n] = alpha * sum_k A[m,k]*B[n,k] (+bias[n]); A,B bf16 K-contiguous.
// 512 thr = 8 waves (2M x 4N), strided frags: m-frag f at wm+f*32, n-frag g at
// wn+g*64. LDS As/Bs[2 dbuf][2 rowhalf][128][64] u16; swizzle phys granule = g^(row&7).
// Phase = {ds_reads; stage; [counted vmcnt]; BAR; setprio(1) MFMA setprio(0)}.
// Counted vmcnt(4) at p3/p7 pre-barrier; steady 12 loads in flight, never 0.
// SMAX 1 = scores epilogue: write exp(alpha*acc) bf16 + per-block row-sum partials.
template <int BIAS_MODE, int SMAX>
__global__ __launch_bounds__(512, 2) void gemm8p(
    const u16* __restrict__ Ag, int lda, long sA,
    const u16* __restrict__ Bg, int ldb, long sB,
    u16* __restrict__ Cg, int ldc, long sC,
    const float* __restrict__ bias, float alpha, int K,
    float* __restrict__ smx) {
  __shared__ u16 As[2][2][8192];
  __shared__ u16 Bs[2][2][8192];
  __shared__ float ps[4][256];
  int bx, by, bz;
  xcd_swz(bx, by, bz);
  const u16* A  = Ag + (size_t)bz * sA;
  const u16* Bm = Bg + (size_t)bz * sB;
  u16* Cb = Cg + (size_t)bz * sC;
  const int bm = by * 256, bn = bx * 256;
  const int tid = threadIdx.x;
  const int wid = tid >> 6, lane = tid & 63;
  const int wm = (wid >> 2) * 16, wn = (wid & 3) * 16;
  const int lr = lane & 15, lh = lane >> 4;
  const int x7 = lr & 7;
  const int g0 = (lh ^ x7) * 8, g1 = ((4 | lh) ^ x7) * 8;  // swizzled granule offs (kh=0/1)

  // staging: wave w covers rows w*8..w*8+7 (+64) of each half; pre-swizzled source
  const int sg = (lane & 7) ^ ((lane >> 3) & 7);
  const u16* Abase = A  + (size_t)(bm + wid * 8 + (lane >> 3)) * lda + sg * 8;
  const u16* Bbase = Bm + (size_t)(bn + wid * 8 + (lane >> 3)) * ldb + sg * 8;

#define STGA(D, H, T) do {                                                   \
    const u16* _s = Abase + (size_t)((H) * 128) * lda + (size_t)(T) * 64;    \
    g2lds16(_s,                    &As[D][H][wid * 512]);                    \
    g2lds16(_s + (size_t)64 * lda, &As[D][H][4096 + wid * 512]);             \
  } while (0)
#define STGB(D, H, T) do {                                                   \
    const u16* _s = Bbase + (size_t)((H) * 128) * ldb + (size_t)(T) * 64;    \
    g2lds16(_s,                    &Bs[D][H][wid * 512]);                    \
    g2lds16(_s + (size_t)64 * ldb, &Bs[D][H][4096 + wid * 512]);             \
  } while (0)

  // bias preload FIRST: its 4 loads are oldest, drained by the prologue vmcnt(4)
  float bias_v[4] = {0.f, 0.f, 0.f, 0.f};
  if (BIAS_MODE == 1) {
#pragma unroll
    for (int g = 0; g < 4; ++g) bias_v[g] = bias[bn + wn + g * 64 + lr];
  }
  SCHED0();

  f32x4 acc[8][4];
  const f32x4 zero = {0.f, 0.f, 0.f, 0.f};
#pragma unroll
  for (int i = 0; i < 8; ++i)
#pragma unroll
    for (int j = 0; j < 4; ++j) acc[i][j] = zero;

  bf16x8 a_[4][2], b_[4][2];

#define RDA(D, AH) do {                                                      \
    _Pragma("unroll") for (int i = 0; i < 4; ++i) {                          \
      const int _o = (wm + i * 32 + lr) * 64;                                \
      a_[i][0] = *(const bf16x8*)&As[D][AH][_o + g0];                        \
      a_[i][1] = *(const bf16x8*)&As[D][AH][_o + g1];                        \
    } } while (0)
#define RDB(D, BH) do {                                                      \
    _Pragma("unroll") for (int j = 0; j < 2; ++j) {                          \
      const int _o = (wn + j * 64 + lr) * 64;                                \
      b_[(BH) * 2 + j][0] = *(const bf16x8*)&Bs[D][BH][_o + g0];             \
      b_[(BH) * 2 + j][1] = *(const bf16x8*)&Bs[D][BH][_o + g1];             \
    } } while (0)
#define MM(AH, BH) do {                                                      \
    __builtin_amdgcn_s_setprio(1);                                           \
    _Pragma("unroll") for (int i = 0; i < 4; ++i)                            \
    _Pragma("unroll") for (int j = 0; j < 2; ++j) {                          \
      acc[(AH) * 4 + i][(BH) * 2 + j] = __builtin_amdgcn_mfma_f32_16x16x32_bf16( \
          a_[i][0], b_[(BH) * 2 + j][0], acc[(AH) * 4 + i][(BH) * 2 + j], 0, 0, 0); \
      acc[(AH) * 4 + i][(BH) * 2 + j] = __builtin_amdgcn_mfma_f32_16x16x32_bf16( \
          a_[i][1], b_[(BH) * 2 + j][1], acc[(AH) * 4 + i][(BH) * 2 + j], 0, 0, 0); \
    }                                                                        \
    __builtin_amdgcn_s_setprio(0);                                           \
  } while (0)

  // prologue: tile0 all 4 halves, then tile1 A0,B1; drain tile0 BEFORE the barrier
  STGA(0, 0, 0); STGB(0, 1, 0); STGA(0, 1, 0); STGB(0, 0, 0);
  STGA(1, 0, 1); STGB(1, 1, 1);
  WAITV4;
  BAR();

  const int nt = K >> 6;  // even, >= 4
  for (int i = 0; i < nt / 2; ++i) {
    const int t1 = 2 * i + 1, t2 = 2 * i + 2, t3 = 2 * i + 3;
    const bool s2 = t2 < nt, s3 = t3 < nt;
    // p0 (d0, A0,B0)
    RDA(0, 0); RDB(0, 0);
    STGB(1, 0, t1);
    BAR(); MM(0, 0);
    // p1 (d0, A0,B1)
    RDB(0, 1);
    STGA(1, 1, t1);
    BAR(); MM(0, 1);
    // p2 (d0, A1,B1)
    RDA(0, 1);
    if (s2) STGA(0, 0, t2);
    BAR(); MM(1, 1);
    // p3 (d0, A1,B0) — counted drain of d1's stages before the phase barrier
    if (s2) STGB(0, 1, t2);
    if (s2) { WAITV4; } else { WAITV0; }
    BAR(); MM(1, 0);
    // p4 (d1, A0,B0)
    RDA(1, 0); RDB(1, 0);
    if (s2) STGA(0, 1, t2);
    BAR(); MM(0, 0);
    // p5 (d1, A0,B1)
    RDB(1, 1);
    if (s2) STGB(0, 0, t2);
    BAR(); MM(0, 1);
    // p6 (d1, A1,B1)
    RDA(1, 1);
    if (s3) STGA(1, 0, t3);
    BAR(); MM(1, 1);
    // p7 (d1, A1,B0) — counted drain of next d0's stages before the phase barrier
    if (s3) STGB(1, 1, t3);
    if (s3) { WAITV4; }
    BAR(); MM(1, 0);
  }
#undef STGA
#undef STGB
#undef RDA
#undef RDB
#undef MM
  SCHED0();

  if (SMAX) {
    // P = exp(alpha*s) bf16 + per-(row, col-block) partial sums -> smx
    float rs[8][4];
#pragma unroll
    for (int f = 0; f < 8; ++f) {
      const int row0 = bm + wm + f * 32 + lh * 4;
#pragma unroll
      for (int r = 0; r < 4; ++r) rs[f][r] = 0.f;
#pragma unroll
      for (int g = 0; g < 4; ++g) {
        const int col = bn + wn + g * 64 + lr;
#pragma unroll
        for (int r = 0; r < 4; ++r) {
          const float e = __expf(acc[f][g][r] * alpha);
          rs[f][r] += e;
          Cb[(size_t)(row0 + r) * ldc + col] = f2bf(e);
        }
      }
#pragma unroll
      for (int r = 0; r < 4; ++r) {
        float v = rs[f][r];
        v += __shfl_xor(v, 1, 64);
        v += __shfl_xor(v, 2, 64);
        v += __shfl_xor(v, 4, 64);
        v += __shfl_xor(v, 8, 64);
        rs[f][r] = v;
      }
    }
    // cross-wave (over wn) reduction: compile-time-predicated LDS writes
#pragma unroll
    for (int f = 0; f < 8; ++f)
#pragma unroll
      for (int r = 0; r < 4; ++r)
        if (lr == ((f << 1) | (r >> 1)))
          ps[wid & 3][wm + f * 32 + lh * 4 + r] = rs[f][r];
    __syncthreads();
    if (tid < 256) {
      const float tot = ps[0][tid] + ps[1][tid] + ps[2][tid] + ps[3][tid];
      smx[((size_t)(bz * 16 + bx) << 12) + bm + tid] = tot;
    }
  } else {
#pragma unroll
    for (int f = 0; f < 8; ++f) {
      const int row0 = bm + wm + f * 32 + lh * 4;
#pragma unroll
      for (int g = 0; g < 4; ++g) {
        const int col = bn + wn + g * 64 + lr;
#pragma unroll
        for (int r = 0; r < 4; ++r)
          Cb[(size_t)(row0 + r) * ldc + col] = f2bf(acc[f][g][r] * alpha + bias_v[g]);
      }
    }
  }
}

// ======= 128x128 PV GEMM — 4 waves, 64 KB LDS, 2 blocks/CU (m97 TLP mechanism) =======
// ha[b*S+i, c] = sum_j P_b[i,j] * V[c, b*4096+j]; K = 4096 (64 K-tiles), no split-K.
// 256 thr = 4 waves (2m x 2n), per-wave 64x64 (acc = 64 regs). LDS: As/Bs[2 dbuf]
// [2 rowhalf][64 rows][64 K] u16 = 64 KB -> 2 blocks/CU; the co-resident block's
// waves cover this block's barrier/vmcnt stalls (m97/m114 mechanism).
// Swizzle identical to gemm8p: phys granule = logical ^ (row&7), pre-swizzled src.
// Each wave reads ONLY its own A-rowhalf (wid>>1) and B-rowhalf (wid&1):
// 16 b128/wave/K-tile. One barrier + one counted drain per K-tile, 32 MFMA/barrier.
// Ledger: stages for tile t issued during t-1 (after t-1's BAR -> WAR-safe);
// WAITV0 at t's top drains them (issued a full K-tile ago); BAR -> cross-wave safe.
__global__ __launch_bounds__(256, 2) void gemm128pv(
    const u16* __restrict__ Pg, const u16* __restrict__ Vg,
    u16* __restrict__ Og, int K) {
  __shared__ u16 As[2][2][4096];
  __shared__ u16 Bs[2][2][4096];
  int bx, by, bz;
  xcd_swz(bx, by, bz);   // grid (4, 32, 4)
  const u16* A  = Pg + (size_t)bz * 16777216;   // P[b]: [4096][4096]
  const u16* Bm = Vg + (size_t)bz * 4096;       // vv[c][16384], col offset b*4096
  u16* Cb = Og + (size_t)bz * 2097152;          // ha[b]: [4096][512]
  const int bm = by * 128, bn = bx * 128;
  const int tid = threadIdx.x;
  const int wid = tid >> 6, lane = tid & 63;
  const int wm = (wid >> 1) * 64, wn = (wid & 1) * 64;
  const int AH = wid >> 1, BH = wid & 1;
  const int lr = lane & 15, lh = lane >> 4;
  const int x7 = lr & 7;
  const int g0 = (lh ^ x7) * 8, g1 = ((4 | lh) ^ x7) * 8;

  // staging: wave w covers local rows w*8..w*8+7 and 32+w*8.. of each 64-row half
  const int sg = (lane & 7) ^ ((lane >> 3) & 7);
  const u16* Asrc = A  + (size_t)(bm + wid * 8 + (lane >> 3)) * 4096 + sg * 8;
  const u16* Bsrc = Bm + (size_t)(bn + wid * 8 + (lane >> 3)) * 16384 + sg * 8;

#define PSTG(D, T) do {                                                      \
    const size_t _ko = (size_t)(T) * 64;                                     \
    g2lds16(Asrc + _ko,                        &As[D][0][wid * 512]);        \
    g2lds16(Asrc + (size_t)32 * 4096 + _ko,    &As[D][0][2048 + wid * 512]); \
    g2lds16(Asrc + (size_t)64 * 4096 + _ko,    &As[D][1][wid * 512]);        \
    g2lds16(Asrc + (size_t)96 * 4096 + _ko,    &As[D][1][2048 + wid * 512]); \
    g2lds16(Bsrc + _ko,                        &Bs[D][0][wid * 512]);        \
    g2lds16(Bsrc + (size_t)32 * 16384 + _ko,   &Bs[D][0][2048 + wid * 512]); \
    g2lds16(Bsrc + (size_t)64 * 16384 + _ko,   &Bs[D][1][wid * 512]);        \
    g2lds16(Bsrc + (size_t)96 * 16384 + _ko,   &Bs[D][1][2048 + wid * 512]); \
  } while (0)

  f32x4 acc[4][4];
  const f32x4 zero = {0.f, 0.f, 0.f, 0.f};
#pragma unroll
  for (int i = 0; i < 4; ++i)
#pragma unroll
    for (int j = 0; j < 4; ++j) acc[i][j] = zero;

  PSTG(0, 0);
  const int nt = K >> 6;
  for (int t = 0; t < nt; ++t) {
    const int d = t & 1;
    WAITV0;            // drain tile t's stages (issued a full K-tile ago)
    BAR();             // all waves drained -> cross-wave visibility; t-1 readers done
    if (t + 1 < nt) PSTG(d ^ 1, t + 1);
    bf16x8 a0_[4], a1_[4], b0_[4], b1_[4];
#pragma unroll
    for (int m = 0; m < 4; ++m) {
      const int ro = (m * 16 + lr) * 64;
      a0_[m] = *(const bf16x8*)&As[d][AH][ro + g0];
      a1_[m] = *(const bf16x8*)&As[d][AH][ro + g1];
      b0_[m] = *(const bf16x8*)&Bs[d][BH][ro + g0];
      b1_[m] = *(const bf16x8*)&Bs[d][BH][ro + g1];
    }
    __builtin_amdgcn_s_setprio(1);
#pragma unroll
    for (int m = 0; m < 4; ++m)
#pragma unroll
      for (int n = 0; n < 4; ++n)
        acc[m][n] = __builtin_amdgcn_mfma_f32_16x16x32_bf16(a0_[m], b0_[n], acc[m][n], 0, 0, 0);
#pragma unroll
    for (int m = 0; m < 4; ++m)
#pragma unroll
      for (int n = 0; n < 4; ++n)
        acc[m][n] = __builtin_amdgcn_mfma_f32_16x16x32_bf16(a1_[m], b1_[n], acc[m][n], 0, 0, 0);
    __builtin_amdgcn_s_setprio(0);
  }
#undef PSTG
  SCHED0();

#pragma unroll
  for (int m = 0; m < 4; ++m) {
    const int row0 = bm + wm + m * 16 + lh * 4;
#pragma unroll
    for (int n = 0; n < 4; ++n) {
      const int col = bn + wn + n * 16 + lr;
#pragma unroll
      for (int r = 0; r < 4; ++r)
        Cb[(size_t)(row0 + r) * 512 + col] = f2bf(acc[m][n][r]);
    }
  }
}

// ---------------- 128x128 GEMM (V-proj and out-proj) ----------------
// OUT_MODE=1: fp32 out[b,o,s] = acc*lscale[n] + bias[m] + xres, n = b*S+s.
#define GBM 128
#define GBN 128
#define GBK 64

template <int BIAS_MODE, int OUT_MODE>
__global__ __launch_bounds__(256) void gemm_abT(
    const u16* __restrict__ Ag, int lda, long sA,
    const u16* __restrict__ Bg, int ldb, long sB,
    void* __restrict__ Cg, int ldc, long sC,
    const float* __restrict__ bias, float alpha,
    const float* __restrict__ xres, const float* __restrict__ lscale, int K) {
  __shared__ u16 As[GBM * GBK];
  __shared__ u16 Bs[GBN * GBK];
  const int bz = blockIdx.z;
  const u16* A    = Ag + (size_t)bz * sA;
  const u16* Bmat = Bg + (size_t)bz * sB;
  const int bm = blockIdx.y * GBM, bn = blockIdx.x * GBN;
  const int tid = threadIdx.x;
  const int wid = tid >> 6, lane = tid & 63;
  const int wm = (wid >> 1) * 64, wn = (wid & 1) * 64;
  const int lr = lane & 15, lh = lane >> 4;
  const int srow = lane >> 3, scol = (lane & 7) * 8;

  f32x4 acc[4][4];
  const f32x4 zero = {0.f, 0.f, 0.f, 0.f};
#pragma unroll
  for (int i = 0; i < 4; ++i)
#pragma unroll
    for (int j = 0; j < 4; ++j) acc[i][j] = zero;

  for (int k0 = 0; k0 < K; k0 += GBK) {
    __syncthreads();
#pragma unroll
    for (int i = 0; i < 4; ++i) {
      const int chunk = wid * 4 + i;
      const int row   = chunk * 8 + srow;
      g2lds16(A    + (size_t)(bm + row) * lda + (k0 + scol), &As[chunk * 512]);
      g2lds16(Bmat + (size_t)(bn + row) * ldb + (k0 + scol), &Bs[chunk * 512]);
    }
    __syncthreads();
#pragma unroll
    for (int ks = 0; ks < 2; ++ks) {
      bf16x8 a_[4], b_[4];
#pragma unroll
      for (int m = 0; m < 4; ++m)
        a_[m] = *(const bf16x8*)&As[(wm + m * 16 + lr) * GBK + ks * 32 + lh * 8];
#pragma unroll
      for (int n = 0; n < 4; ++n)
        b_[n] = *(const bf16x8*)&Bs[(wn + n * 16 + lr) * GBK + ks * 32 + lh * 8];
#pragma unroll
      for (int m = 0; m < 4; ++m)
#pragma unroll
        for (int n = 0; n < 4; ++n)
          acc[m][n] = __builtin_amdgcn_mfma_f32_16x16x32_bf16(a_[m], b_[n], acc[m][n], 0, 0, 0);
    }
  }

  if (OUT_MODE == 0) {
    u16* Cb = (u16*)Cg + (size_t)bz * sC;
#pragma unroll
    for (int m = 0; m < 4; ++m) {
      const int row0 = bm + wm + m * 16 + lh * 4;
#pragma unroll
      for (int n = 0; n < 4; ++n) {
        const int col = bn + wn + n * 16 + lr;
        float bn_ = (BIAS_MODE == 1) ? bias[col] : 0.f;
#pragma unroll
        for (int r = 0; r < 4; ++r) {
          float bb = (BIAS_MODE == 2) ? bias[row0 + r] : bn_;
          Cb[(size_t)(row0 + r) * ldc + col] = f2bf(acc[m][n][r] * alpha + bb);
        }
      }
    }
  } else {
    float* Ob = (float*)Cg;
#pragma unroll
    for (int m = 0; m < 4; ++m) {
      const int row0 = bm + wm + m * 16 + lh * 4;
#pragma unroll
      for (int n = 0; n < 4; ++n) {
        const int col = bn + wn + n * 16 + lr;
        const int bb = col >> 12, sp = col & (S_ - 1);
        const float lsc = lscale[col];
#pragma unroll
        for (int r = 0; r < 4; ++r) {
          const int o = row0 + r;
          const size_t idx = ((size_t)bb * C_ + o) * S_ + sp;
          Ob[idx] = acc[m][n][r] * lsc + bias[o] + xres[idx];
        }
      }
    }
  }
}

extern "C" void kernel_launch(void* const* d_in, const int* in_sizes, int n_in,
                              void* d_out, int out_size, void* d_ws, size_t ws_size,
                              hipStream_t stream) {
  const float* x     = (const float*)d_in[0];
  const float* gamma = (const float*)d_in[1];
  const float* beta  = (const float*)d_in[2];
  const float* wq = (const float*)d_in[3];
  const float* bq = (const float*)d_in[4];
  const float* wk = (const float*)d_in[5];
  const float* bk = (const float*)d_in[6];
  const float* wv = (const float*)d_in[7];
  const float* bv = (const float*)d_in[8];
  const float* wo = (const float*)d_in[9];
  const float* bo = (const float*)d_in[10];
  float* out = (float*)d_out;

  // ws: stats 1KB | weights bf16 4x512KB | bqk 4KB | ht 16MB | qkt 32MB | vv 16MB
  //     | sc 128MB | partials 1MB | Lr 64KB
  char* ws = (char*)d_ws;
  float* stats = (float*)ws;
  u16* wqb = (u16*)(ws + 1024);
  u16* wkb = wqb + 262144;   // contiguous after wqb -> [wq;wk] is one 1024x512 matrix
  u16* wvb = wkb + 262144;
  u16* wob = wvb + 262144;
  float* bqk = (float*)(wob + 262144);
  u16* ht  = (u16*)((char*)bqk + 4096);  // [B*S, C]
  u16* qkt = ht + 8388608;               // [B*S, 1024] (q|k); later ha (PV output)
  u16* vv  = qkt + 16777216;             // [C, B*S]
  u16* sc  = vv + 8388608;               // [B, S, S] exp(scores)
  float* partials = (float*)(sc + 67108864);  // [B][16][4096]
  float* Lr = partials + 262144;              // [B][4096]

  f32_to_bf16<<<1024, 256, 0, stream>>>(wq, wqb, 262144);
  f32_to_bf16<<<1024, 256, 0, stream>>>(wk, wkb, 262144);
  f32_to_bf16<<<1024, 256, 0, stream>>>(wv, wvb, 262144);
  f32_to_bf16<<<1024, 256, 0, stream>>>(wo, wob, 262144);
  concat_bias<<<4, 256, 0, stream>>>(bq, bk, bqk);

  gn_stats<<<128, 256, 0, stream>>>(x, stats);
  gn_apply_t<<<dim3(128, 16, 4), dim3(32, 8), 0, stream>>>(x, gamma, beta, stats, ht);

  // fused Q|K projection: qkt[bs, 0:512]=Q, [512:1024]=K   (256 blocks)
  gemm8p<1, 0><<<dim3(4, 64, 1), 512, 0, stream>>>(ht, 512, 0, wqb, 512, 0,
                                                   qkt, 1024, 0, bqk, 1.f, 512, nullptr);
  // V[c, b*S+s]: bias per m (=c)                            (512 blocks)
  gemm_abT<2, 0><<<dim3(128, 4, 1), 256, 0, stream>>>(wvb, 512, 0, ht, 512, 0,
                                                      vv, 16384, 0, bv, 1.f,
                                                      nullptr, nullptr, 512);
  // P[b,i,j] = exp(scale * Q.K) + row-sum partials          (1024 blocks)
  gemm8p<0, 1><<<dim3(16, 16, 4), 512, 0, stream>>>(qkt, 1024, 4194304, qkt + 512, 1024, 4194304,
                                                    sc, 4096, 16777216, nullptr,
                                                    0.04419417382415922f, 512, partials);
  reduce_l<<<64, 256, 0, stream>>>(partials, Lr);
  // PV (unsplit, K=4096): ha = qkt region (dead after scores)   (512 blocks, 2/CU)
  gemm128pv<<<dim3(4, 32, 4), 256, 0, stream>>>(sc, vv, qkt, 4096);
  // out[b,o,s] = (Wo @ ha) * Lr[bs] + bo + x                (512 blocks)
  gemm_abT<2, 1><<<dim3(128, 4, 1), 256, 0, stream>>>(wob, 512, 0, qkt, 512, 0,
                                                      out, 0, 0, bo, 1.f,
                                                      x, Lr, 512);
}

// Round 15
// 294.711 us; speedup vs baseline: 1.1116x; 1.0049x over previous
//
#include <hip/hip_runtime.h>

#define B_   4
#define C_   512
#define S_   4096
#define G_   32
#define CPG_ 16
#define EPS_ 1e-6f

typedef unsigned short u16;
typedef __bf16 bf16x8 __attribute__((ext_vector_type(8)));
typedef float  f32x4  __attribute__((ext_vector_type(4)));

__device__ __forceinline__ u16 f2bf(float f) {
  unsigned u = __float_as_uint(f);
  u += 0x7fffu + ((u >> 16) & 1u);   // RNE
  return (u16)(u >> 16);
}
__device__ __forceinline__ float bf2f(u16 h) {
  return __uint_as_float((unsigned)h << 16);
}

__device__ __forceinline__ void g2lds16(const void* g, void* l) {
  __builtin_amdgcn_global_load_lds(
      (const __attribute__((address_space(1))) void*)g,
      (__attribute__((address_space(3))) void*)l, 16, 0, 0);
}

#define BAR()    __builtin_amdgcn_s_barrier()
#define SCHED0() __builtin_amdgcn_sched_barrier(0)
#define WAITV4   asm volatile("s_waitcnt vmcnt(4)" ::: "memory")
#define WAITV0   asm volatile("s_waitcnt vmcnt(0)" ::: "memory")

// chunked XCD swizzle (bijective when nwg % 8 == 0 — all grids here satisfy it)
__device__ __forceinline__ void xcd_swz(int& bx, int& by, int& bz) {
  const int gx = gridDim.x, gy = gridDim.y;
  const int nwg = gx * gy * (int)gridDim.z;
  const int flat = blockIdx.x + gx * (blockIdx.y + gy * blockIdx.z);
  const int q = nwg >> 3;
  const int nf = (flat & 7) * q + (flat >> 3);
  bx = nf % gx;
  const int r = nf / gx;
  by = r % gy;
  bz = r / gy;
}

// ---------------- fp32 -> bf16 weight conversion ----------------
__global__ __launch_bounds__(256) void f32_to_bf16(const float* __restrict__ in,
                                                   u16* __restrict__ out, int n) {
  int i = blockIdx.x * 256 + threadIdx.x;
  if (i < n) out[i] = f2bf(in[i]);
}

__global__ __launch_bounds__(256) void concat_bias(const float* __restrict__ a,
                                                   const float* __restrict__ b,
                                                   float* __restrict__ o) {
  int i = blockIdx.x * 256 + threadIdx.x;  // grid 4 -> 1024
  o[i] = (i < 512) ? a[i] : b[i - 512];
}

// ---------------- softmax denominator: Lr[b,i] = 1/sum_jb partial ----------------
__global__ __launch_bounds__(256) void reduce_l(const float* __restrict__ p,
                                                float* __restrict__ lr) {
  const int i = blockIdx.x * 256 + threadIdx.x;   // 16384 = B*S
  const int b = i >> 12, row = i & 4095;
  float s = 0.f;
#pragma unroll
  for (int jb = 0; jb < 16; ++jb) s += p[((size_t)(b * 16 + jb) << 12) + row];
  lr[i] = 1.f / s;
}

// ---------------- GroupNorm stats: one block per (b,g) ----------------
__global__ __launch_bounds__(256) void gn_stats(const float* __restrict__ x,
                                                float* __restrict__ stats) {
  const int bg = blockIdx.x;
  const float4* p4 = (const float4*)(x + (size_t)bg * (CPG_ * S_));
  float s = 0.f, ss = 0.f;
  const int tid = threadIdx.x;
  for (int i = tid; i < CPG_ * S_ / 4; i += 256) {
    float4 v = p4[i];
    s  += v.x + v.y + v.z + v.w;
    ss += v.x * v.x + v.y * v.y + v.z * v.z + v.w * v.w;
  }
#pragma unroll
  for (int o = 32; o; o >>= 1) { s += __shfl_xor(s, o, 64); ss += __shfl_xor(ss, o, 64); }
  __shared__ float sm[8];
  const int wid = tid >> 6, lane = tid & 63;
  if (lane == 0) { sm[wid * 2] = s; sm[wid * 2 + 1] = ss; }
  __syncthreads();
  if (tid == 0) {
    s  = sm[0] + sm[2] + sm[4] + sm[6];
    ss = sm[1] + sm[3] + sm[5] + sm[7];
    const float inv = 1.f / (float)(CPG_ * S_);
    float mu = s * inv;
    float var = ss * inv - mu * mu;
    stats[bg * 2]     = mu;
    stats[bg * 2 + 1] = rsqrtf(var + EPS_);
  }
}

// ---------------- normalize + transpose: x[b,c,s] -> ht[b*s, c] bf16 ----------------
__global__ __launch_bounds__(256) void gn_apply_t(const float* __restrict__ x,
                                                  const float* __restrict__ gamma,
                                                  const float* __restrict__ beta,
                                                  const float* __restrict__ stats,
                                                  u16* __restrict__ ht) {
  __shared__ float tile[32][33];
  const int b = blockIdx.z, c0 = blockIdx.y * 32, s0 = blockIdx.x * 32;
  const int tx = threadIdx.x, ty = threadIdx.y;
#pragma unroll
  for (int i = 0; i < 4; ++i) {
    const int c  = c0 + ty + i * 8;
    const float mu = stats[(b * G_ + (c >> 4)) * 2];
    const float rs = stats[(b * G_ + (c >> 4)) * 2 + 1];
    const float v  = x[((size_t)b * C_ + c) * S_ + s0 + tx];
    tile[ty + i * 8][tx] = (v - mu) * rs * gamma[c] + beta[c];
  }
  __syncthreads();
#pragma unroll
  for (int i = 0; i < 4; ++i) {
    const int s = s0 + ty + i * 8;
    ht[((size_t)b * S_ + s) * C_ + c0 + tx] = f2bf(tile[tx][ty + i * 8]);
  }
}

// ======= 256x256 8-phase GEMM — R12 exact (16x16x32, single barrier/phase) =======
// C[m,n] = alpha * sum_k A[m,k]*B[n,k] (+bias[n]); A,B bf16 K-contiguous.
// 512 thr = 8 waves (2M x 4N), strided frags: m-frag f at wm+f*32, n-frag g at
// wn+g*64. LDS As/Bs[2 dbuf][2 half][128][64] u16; swizzle phys granule = g^(row&7).
// Phase = {ds_reads; stage; [counted vmcnt]; BAR; setprio(1) MFMA setprio(0)}.
// NO hard lgkmcnt(0): compiler emits per-fragment counted lgkm waits so MFMA
// starts as soon as its first frags land; next phase's reads/stages issue under
// the MFMA tail. Counted vmcnt(4) at p3/p7 pre-barrier (asm volatile,
// unhoistable) drains exactly the 8 loads of the dbuf read next; steady state
// 12 loads in flight, never 0.
// ZMODE 1 = PV split-K: bz -> (b = bz>>1, kh = bz&1), hardcoded offsets.
// SMAX 1 = scores epilogue: P = exp2(alpha*acc) bf16 (alpha pre-multiplied by
// log2(e) on host) + per-block row-sum partials.
template <int BIAS_MODE, int ZMODE, int SMAX>
__global__ __launch_bounds__(512, 2) void gemm8p(
    const u16* __restrict__ Ag, int lda, long sA,
    const u16* __restrict__ Bg, int ldb, long sB,
    u16* __restrict__ Cg, int ldc, long sC,
    const float* __restrict__ bias, float alpha, int K,
    float* __restrict__ smx) {
  __shared__ u16 As[2][2][8192];
  __shared__ u16 Bs[2][2][8192];
  __shared__ float ps[4][256];
  int bx, by, bz;
  xcd_swz(bx, by, bz);
  const u16 *A, *Bm;
  u16* Cb;
  if (ZMODE == 0) {
    A = Ag + (size_t)bz * sA; Bm = Bg + (size_t)bz * sB; Cb = Cg + (size_t)bz * sC;
  } else {  // PV split-K: A = P[b], cols kh*2048+; B = V rows, cols b*4096+kh*2048+
    const int b = bz >> 1, kh = bz & 1;
    A  = Ag + (size_t)b * 16777216 + (size_t)kh * 2048;
    Bm = Bg + (size_t)b * 4096 + (size_t)kh * 2048;
    Cb = Cg + (size_t)kh * 8388608 + (size_t)b * 2097152;
  }
  const int bm = by * 256, bn = bx * 256;
  const int tid = threadIdx.x;
  const int wid = tid >> 6, lane = tid & 63;
  const int wm = (wid >> 2) * 16, wn = (wid & 3) * 16;
  const int lr = lane & 15, lh = lane >> 4;
  const int x7 = lr & 7;
  const int g0 = (lh ^ x7) * 8, g1 = ((4 | lh) ^ x7) * 8;  // swizzled granule offs (kh=0/1)

  // staging: wave w covers rows w*8..w*8+7 (+64) of each half; pre-swizzled source
  const int sg = (lane & 7) ^ ((lane >> 3) & 7);
  const u16* Abase = A  + (size_t)(bm + wid * 8 + (lane >> 3)) * lda + sg * 8;
  const u16* Bbase = Bm + (size_t)(bn + wid * 8 + (lane >> 3)) * ldb + sg * 8;

#define STGA(D, H, T) do {                                                   \
    const u16* _s = Abase + (size_t)((H) * 128) * lda + (size_t)(T) * 64;    \
    g2lds16(_s,                    &As[D][H][wid * 512]);                    \
    g2lds16(_s + (size_t)64 * lda, &As[D][H][4096 + wid * 512]);             \
  } while (0)
#define STGB(D, H, T) do {                                                   \
    const u16* _s = Bbase + (size_t)((H) * 128) * ldb + (size_t)(T) * 64;    \
    g2lds16(_s,                    &Bs[D][H][wid * 512]);                    \
    g2lds16(_s + (size_t)64 * ldb, &Bs[D][H][4096 + wid * 512]);             \
  } while (0)

  // bias preload FIRST: its 4 loads are oldest, drained by the prologue vmcnt(4)
  float bias_v[4] = {0.f, 0.f, 0.f, 0.f};
  if (BIAS_MODE == 1) {
#pragma unroll
    for (int g = 0; g < 4; ++g) bias_v[g] = bias[bn + wn + g * 64 + lr];
  }
  SCHED0();

  f32x4 acc[8][4];
  const f32x4 zero = {0.f, 0.f, 0.f, 0.f};
#pragma unroll
  for (int i = 0; i < 8; ++i)
#pragma unroll
    for (int j = 0; j < 4; ++j) acc[i][j] = zero;

  bf16x8 a_[4][2], b_[4][2];

#define RDA(D, AH) do {                                                      \
    _Pragma("unroll") for (int i = 0; i < 4; ++i) {                          \
      const int _o = (wm + i * 32 + lr) * 64;                                \
      a_[i][0] = *(const bf16x8*)&As[D][AH][_o + g0];                        \
      a_[i][1] = *(const bf16x8*)&As[D][AH][_o + g1];                        \
    } } while (0)
#define RDB(D, BH) do {                                                      \
    _Pragma("unroll") for (int j = 0; j < 2; ++j) {                          \
      const int _o = (wn + j * 64 + lr) * 64;                                \
      b_[(BH) * 2 + j][0] = *(const bf16x8*)&Bs[D][BH][_o + g0];             \
      b_[(BH) * 2 + j][1] = *(const bf16x8*)&Bs[D][BH][_o + g1];             \
    } } while (0)
#define MM(AH, BH) do {                                                      \
    __builtin_amdgcn_s_setprio(1);                                           \
    _Pragma("unroll") for (int i = 0; i < 4; ++i)                            \
    _Pragma("unroll") for (int j = 0; j < 2; ++j) {                          \
      acc[(AH) * 4 + i][(BH) * 2 + j] = __builtin_amdgcn_mfma_f32_16x16x32_bf16( \
          a_[i][0], b_[(BH) * 2 + j][0], acc[(AH) * 4 + i][(BH) * 2 + j], 0, 0, 0); \
      acc[(AH) * 4 + i][(BH) * 2 + j] = __builtin_amdgcn_mfma_f32_16x16x32_bf16( \
          a_[i][1], b_[(BH) * 2 + j][1], acc[(AH) * 4 + i][(BH) * 2 + j], 0, 0, 0); \
    }                                                                        \
    __builtin_amdgcn_s_setprio(0);                                           \
  } while (0)

  // prologue: tile0 all 4 halves, then tile1 A0,B1; drain tile0 BEFORE the barrier
  STGA(0, 0, 0); STGB(0, 1, 0); STGA(0, 1, 0); STGB(0, 0, 0);
  STGA(1, 0, 1); STGB(1, 1, 1);
  WAITV4;
  BAR();

  const int nt = K >> 6;  // even, >= 4
  for (int i = 0; i < nt / 2; ++i) {
    const int t1 = 2 * i + 1, t2 = 2 * i + 2, t3 = 2 * i + 3;
    const bool s2 = t2 < nt, s3 = t3 < nt;
    // p0 (d0, A0,B0)
    RDA(0, 0); RDB(0, 0);
    STGB(1, 0, t1);
    BAR(); MM(0, 0);
    // p1 (d0, A0,B1)
    RDB(0, 1);
    STGA(1, 1, t1);
    BAR(); MM(0, 1);
    // p2 (d0, A1,B1)
    RDA(0, 1);
    if (s2) STGA(0, 0, t2);
    BAR(); MM(1, 1);
    // p3 (d0, A1,B0) — counted drain of d1's stages before the phase barrier
    if (s2) STGB(0, 1, t2);
    if (s2) { WAITV4; } else { WAITV0; }
    BAR(); MM(1, 0);
    // p4 (d1, A0,B0)
    RDA(1, 0); RDB(1, 0);
    if (s2) STGA(0, 1, t2);
    BAR(); MM(0, 0);
    // p5 (d1, A0,B1)
    RDB(1, 1);
    if (s2) STGB(0, 0, t2);
    BAR(); MM(0, 1);
    // p6 (d1, A1,B1)
    RDA(1, 1);
    if (s3) STGA(1, 0, t3);
    BAR(); MM(1, 1);
    // p7 (d1, A1,B0) — counted drain of next d0's stages before the phase barrier
    if (s3) STGB(1, 1, t3);
    if (s3) { WAITV4; }
    BAR(); MM(1, 0);
  }
#undef STGA
#undef STGB
#undef RDA
#undef RDB
#undef MM
  SCHED0();

  if (SMAX) {
    // P = exp2(alpha*s) bf16 (alpha includes log2 e) + per-block row-sum partials
    float rs[8][4];
#pragma unroll
    for (int f = 0; f < 8; ++f) {
      const int row0 = bm + wm + f * 32 + lh * 4;
#pragma unroll
      for (int r = 0; r < 4; ++r) rs[f][r] = 0.f;
#pragma unroll
      for (int g = 0; g < 4; ++g) {
        const int col = bn + wn + g * 64 + lr;
#pragma unroll
        for (int r = 0; r < 4; ++r) {
          const float e = exp2f(acc[f][g][r] * alpha);
          rs[f][r] += e;
          Cb[(size_t)(row0 + r) * ldc + col] = f2bf(e);
        }
      }
#pragma unroll
      for (int r = 0; r < 4; ++r) {
        float v = rs[f][r];
        v += __shfl_xor(v, 1, 64);
        v += __shfl_xor(v, 2, 64);
        v += __shfl_xor(v, 4, 64);
        v += __shfl_xor(v, 8, 64);
        rs[f][r] = v;
      }
    }
    // cross-wave (over wn) reduction: compile-time-predicated LDS writes
#pragma unroll
    for (int f = 0; f < 8; ++f)
#pragma unroll
      for (int r = 0; r < 4; ++r)
        if (lr == ((f << 1) | (r >> 1)))
          ps[wid & 3][wm + f * 32 + lh * 4 + r] = rs[f][r];
    __syncthreads();
    if (tid < 256) {
      const float tot = ps[0][tid] + ps[1][tid] + ps[2][tid] + ps[3][tid];
      smx[((size_t)(bz * 16 + bx) << 12) + bm + tid] = tot;
    }
  } else {
#pragma unroll
    for (int f = 0; f < 8; ++f) {
      const int row0 = bm + wm + f * 32 + lh * 4;
#pragma unroll
      for (int g = 0; g < 4; ++g) {
        const int col = bn + wn + g * 64 + lr;
#pragma unroll
        for (int r = 0; r < 4; ++r)
          Cb[(size_t)(row0 + r) * ldc + col] = f2bf(acc[f][g][r] * alpha + bias_v[g]);
      }
    }
  }
}

// ---------------- 128x128 GEMM (V-proj and out-proj) ----------------
// BCOMB=1: B-operand is the fp32 sum of two bf16 psum buffers (Bg, Bg2), added
// during reg-staged B-staging (replaces the separate add_scale pass).
// OUT_MODE=1: fp32 out[b,o,s] = acc*lscale[n] + bias[m] + xres, n = b*S+s.
#define GBM 128
#define GBN 128
#define GBK 64

template <int BIAS_MODE, int OUT_MODE, int BCOMB>
__global__ __launch_bounds__(256) void gemm_abT(
    const u16* __restrict__ Ag, int lda, long sA,
    const u16* __restrict__ Bg, int ldb, long sB,
    void* __restrict__ Cg, int ldc, long sC,
    const float* __restrict__ bias, float alpha,
    const float* __restrict__ xres, const float* __restrict__ lscale,
    const u16* __restrict__ Bg2, int K) {
  __shared__ u16 As[GBM * GBK];
  __shared__ u16 Bs[GBN * GBK];
  const int bz = blockIdx.z;
  const u16* A    = Ag + (size_t)bz * sA;
  const u16* Bmat = Bg + (size_t)bz * sB;
  const int bm = blockIdx.y * GBM, bn = blockIdx.x * GBN;
  const int tid = threadIdx.x;
  const int wid = tid >> 6, lane = tid & 63;
  const int wm = (wid >> 1) * 64, wn = (wid & 1) * 64;
  const int lr = lane & 15, lh = lane >> 4;
  const int srow = lane >> 3, scol = (lane & 7) * 8;

  f32x4 acc[4][4];
  const f32x4 zero = {0.f, 0.f, 0.f, 0.f};
#pragma unroll
  for (int i = 0; i < 4; ++i)
#pragma unroll
    for (int j = 0; j < 4; ++j) acc[i][j] = zero;

  for (int k0 = 0; k0 < K; k0 += GBK) {
    __syncthreads();
#pragma unroll
    for (int i = 0; i < 4; ++i) {
      const int chunk = wid * 4 + i;
      const int row   = chunk * 8 + srow;
      g2lds16(A + (size_t)(bm + row) * lda + (k0 + scol), &As[chunk * 512]);
      if (BCOMB == 0) {
        g2lds16(Bmat + (size_t)(bn + row) * ldb + (k0 + scol), &Bs[chunk * 512]);
      } else {
        const size_t boff = (size_t)(bn + row) * ldb + (k0 + scol);
        const uint4 u0 = *(const uint4*)(Bmat + boff);
        const uint4 u1 = *(const uint4*)(Bg2 + boff);
        const unsigned* p0 = (const unsigned*)&u0;
        const unsigned* p1 = (const unsigned*)&u1;
        unsigned rr[4];
#pragma unroll
        for (int k = 0; k < 4; ++k) {
          const float lo = bf2f((u16)(p0[k] & 0xffffu)) + bf2f((u16)(p1[k] & 0xffffu));
          const float hi = bf2f((u16)(p0[k] >> 16)) + bf2f((u16)(p1[k] >> 16));
          rr[k] = (unsigned)f2bf(lo) | ((unsigned)f2bf(hi) << 16);
        }
        *(uint4*)&Bs[chunk * 512 + lane * 8] = *(const uint4*)rr;
      }
    }
    __syncthreads();
#pragma unroll
    for (int ks = 0; ks < 2; ++ks) {
      bf16x8 a_[4], b_[4];
#pragma unroll
      for (int m = 0; m < 4; ++m)
        a_[m] = *(const bf16x8*)&As[(wm + m * 16 + lr) * GBK + ks * 32 + lh * 8];
#pragma unroll
      for (int n = 0; n < 4; ++n)
        b_[n] = *(const bf16x8*)&Bs[(wn + n * 16 + lr) * GBK + ks * 32 + lh * 8];
#pragma unroll
      for (int m = 0; m < 4; ++m)
#pragma unroll
        for (int n = 0; n < 4; ++n)
          acc[m][n] = __builtin_amdgcn_mfma_f32_16x16x32_bf16(a_[m], b_[n], acc[m][n], 0, 0, 0);
    }
  }

  if (OUT_MODE == 0) {
    u16* Cb = (u16*)Cg + (size_t)bz * sC;
#pragma unroll
    for (int m = 0; m < 4; ++m) {
      const int row0 = bm + wm + m * 16 + lh * 4;
#pragma unroll
      for (int n = 0; n < 4; ++n) {
        const int col = bn + wn + n * 16 + lr;
        float bn_ = (BIAS_MODE == 1) ? bias[col] : 0.f;
#pragma unroll
        for (int r = 0; r < 4; ++r) {
          float bb = (BIAS_MODE == 2) ? bias[row0 + r] : bn_;
          Cb[(size_t)(row0 + r) * ldc + col] = f2bf(acc[m][n][r] * alpha + bb);
        }
      }
    }
  } else {
    float* Ob = (float*)Cg;
#pragma unroll
    for (int m = 0; m < 4; ++m) {
      const int row0 = bm + wm + m * 16 + lh * 4;
#pragma unroll
      for (int n = 0; n < 4; ++n) {
        const int col = bn + wn + n * 16 + lr;
        const int bb = col >> 12, sp = col & (S_ - 1);
        const float lsc = lscale[col];
#pragma unroll
        for (int r = 0; r < 4; ++r) {
          const int o = row0 + r;
          const size_t idx = ((size_t)bb * C_ + o) * S_ + sp;
          Ob[idx] = acc[m][n][r] * lsc + bias[o] + xres[idx];
        }
      }
    }
  }
}

extern "C" void kernel_launch(void* const* d_in, const int* in_sizes, int n_in,
                              void* d_out, int out_size, void* d_ws, size_t ws_size,
                              hipStream_t stream) {
  const float* x     = (const float*)d_in[0];
  const float* gamma = (const float*)d_in[1];
  const float* beta  = (const float*)d_in[2];
  const float* wq = (const float*)d_in[3];
  const float* bq = (const float*)d_in[4];
  const float* wk = (const float*)d_in[5];
  const float* bk = (const float*)d_in[6];
  const float* wv = (const float*)d_in[7];
  const float* bv = (const float*)d_in[8];
  const float* wo = (const float*)d_in[9];
  const float* bo = (const float*)d_in[10];
  float* out = (float*)d_out;

  // ws: stats 1KB | weights bf16 4x512KB | bqk 4KB | ht 16MB | qkt 32MB | vv 16MB
  //     | sc 128MB | partials 1MB | Lr 64KB
  char* ws = (char*)d_ws;
  float* stats = (float*)ws;
  u16* wqb = (u16*)(ws + 1024);
  u16* wkb = wqb + 262144;   // contiguous after wqb -> [wq;wk] is one 1024x512 matrix
  u16* wvb = wkb + 262144;
  u16* wob = wvb + 262144;
  float* bqk = (float*)(wob + 262144);
  u16* ht  = (u16*)((char*)bqk + 4096);  // [B*S, C]
  u16* qkt = ht + 8388608;               // [B*S, 1024] (q|k); later PV psum halves
  u16* vv  = qkt + 16777216;             // [C, B*S]
  u16* sc  = vv + 8388608;               // [B, S, S] exp(scores)
  float* partials = (float*)(sc + 67108864);  // [B][16][4096]
  float* Lr = partials + 262144;              // [B][4096]

  f32_to_bf16<<<1024, 256, 0, stream>>>(wq, wqb, 262144);
  f32_to_bf16<<<1024, 256, 0, stream>>>(wk, wkb, 262144);
  f32_to_bf16<<<1024, 256, 0, stream>>>(wv, wvb, 262144);
  f32_to_bf16<<<1024, 256, 0, stream>>>(wo, wob, 262144);
  concat_bias<<<4, 256, 0, stream>>>(bq, bk, bqk);

  gn_stats<<<128, 256, 0, stream>>>(x, stats);
  gn_apply_t<<<dim3(128, 16, 4), dim3(32, 8), 0, stream>>>(x, gamma, beta, stats, ht);

  // fused Q|K projection: qkt[bs, 0:512]=Q, [512:1024]=K   (256 blocks)
  gemm8p<1, 0, 0><<<dim3(4, 64, 1), 512, 0, stream>>>(ht, 512, 0, wqb, 512, 0,
                                                      qkt, 1024, 0, bqk, 1.f, 512, nullptr);
  // V[c, b*S+s]: bias per m (=c)                            (512 blocks)
  gemm_abT<2, 0, 0><<<dim3(128, 4, 1), 256, 0, stream>>>(wvb, 512, 0, ht, 512, 0,
                                                         vv, 16384, 0, bv, 1.f,
                                                         nullptr, nullptr, nullptr, 512);
  // P[b,i,j] = exp2(scale*log2e * Q.K) + row-sum partials   (1024 blocks)
  gemm8p<0, 0, 1><<<dim3(16, 16, 4), 512, 0, stream>>>(qkt, 1024, 4194304, qkt + 512, 1024, 4194304,
                                                       sc, 4096, 16777216, nullptr,
                                                       0.06375871527f, 512, partials);
  reduce_l<<<64, 256, 0, stream>>>(partials, Lr);
  // PV split-K=2 on unnormalized P: psums in qkt halves     (256 blocks)
  gemm8p<0, 1, 0><<<dim3(2, 16, 8), 512, 0, stream>>>(sc, 4096, 0, vv, 16384, 0,
                                                      qkt, 512, 0, nullptr, 1.f, 2048, nullptr);
  // out[b,o,s] = (Wo @ (psum0+psum1)) * Lr[bs] + bo + x      (512 blocks)
  gemm_abT<2, 1, 1><<<dim3(128, 4, 1), 256, 0, stream>>>(wob, 512, 0, qkt, 512, 0,
                                                         out, 0, 0, bo, 1.f,
                                                         x, Lr, qkt + 8388608, 512);
}

// Round 16
// 285.552 us; speedup vs baseline: 1.1472x; 1.0321x over previous
//
#include <hip/hip_runtime.h>

#define B_   4
#define C_   512
#define S_   4096
#define G_   32
#define CPG_ 16
#define EPS_ 1e-6f

typedef unsigned short u16;
typedef __bf16 bf16x8 __attribute__((ext_vector_type(8)));
typedef float  f32x4  __attribute__((ext_vector_type(4)));

__device__ __forceinline__ u16 f2bf(float f) {
  unsigned u = __float_as_uint(f);
  u += 0x7fffu + ((u >> 16) & 1u);   // RNE
  return (u16)(u >> 16);
}
__device__ __forceinline__ float bf2f(u16 h) {
  return __uint_as_float((unsigned)h << 16);
}

__device__ __forceinline__ void g2lds16(const void* g, void* l) {
  __builtin_amdgcn_global_load_lds(
      (const __attribute__((address_space(1))) void*)g,
      (__attribute__((address_space(3))) void*)l, 16, 0, 0);
}

#define BAR()    __builtin_amdgcn_s_barrier()
#define SCHED0() __builtin_amdgcn_sched_barrier(0)
#define WAITV4   asm volatile("s_waitcnt vmcnt(4)" ::: "memory")
#define WAITV0   asm volatile("s_waitcnt vmcnt(0)" ::: "memory")

// chunked XCD swizzle (bijective when nwg % 8 == 0 — all grids here satisfy it)
__device__ __forceinline__ void xcd_swz(int& bx, int& by, int& bz) {
  const int gx = gridDim.x, gy = gridDim.y;
  const int nwg = gx * gy * (int)gridDim.z;
  const int flat = blockIdx.x + gx * (blockIdx.y + gy * blockIdx.z);
  const int q = nwg >> 3;
  const int nf = (flat & 7) * q + (flat >> 3);
  bx = nf % gx;
  const int r = nf / gx;
  by = r % gy;
  bz = r / gy;
}

// ---------------- fp32 -> bf16 weight conversion ----------------
__global__ __launch_bounds__(256) void f32_to_bf16(const float* __restrict__ in,
                                                   u16* __restrict__ out, int n) {
  int i = blockIdx.x * 256 + threadIdx.x;
  if (i < n) out[i] = f2bf(in[i]);
}

__global__ __launch_bounds__(256) void concat_bias(const float* __restrict__ a,
                                                   const float* __restrict__ b,
                                                   float* __restrict__ o) {
  int i = blockIdx.x * 256 + threadIdx.x;  // grid 4 -> 1024
  o[i] = (i < 512) ? a[i] : b[i - 512];
}

// ---------------- softmax denominator: Lr[b,i] = 1/sum_jb partial ----------------
__global__ __launch_bounds__(256) void reduce_l(const float* __restrict__ p,
                                                float* __restrict__ lr) {
  const int i = blockIdx.x * 256 + threadIdx.x;   // 16384 = B*S
  const int b = i >> 12, row = i & 4095;
  float s = 0.f;
#pragma unroll
  for (int jb = 0; jb < 16; ++jb) s += p[((size_t)(b * 16 + jb) << 12) + row];
  lr[i] = 1.f / s;
}

// ---------------- GroupNorm stats: one block per (b,g) ----------------
__global__ __launch_bounds__(256) void gn_stats(const float* __restrict__ x,
                                                float* __restrict__ stats) {
  const int bg = blockIdx.x;
  const float4* p4 = (const float4*)(x + (size_t)bg * (CPG_ * S_));
  float s = 0.f, ss = 0.f;
  const int tid = threadIdx.x;
  for (int i = tid; i < CPG_ * S_ / 4; i += 256) {
    float4 v = p4[i];
    s  += v.x + v.y + v.z + v.w;
    ss += v.x * v.x + v.y * v.y + v.z * v.z + v.w * v.w;
  }
#pragma unroll
  for (int o = 32; o; o >>= 1) { s += __shfl_xor(s, o, 64); ss += __shfl_xor(ss, o, 64); }
  __shared__ float sm[8];
  const int wid = tid >> 6, lane = tid & 63;
  if (lane == 0) { sm[wid * 2] = s; sm[wid * 2 + 1] = ss; }
  __syncthreads();
  if (tid == 0) {
    s  = sm[0] + sm[2] + sm[4] + sm[6];
    ss = sm[1] + sm[3] + sm[5] + sm[7];
    const float inv = 1.f / (float)(CPG_ * S_);
    float mu = s * inv;
    float var = ss * inv - mu * mu;
    stats[bg * 2]     = mu;
    stats[bg * 2 + 1] = rsqrtf(var + EPS_);
  }
}

// ---------------- normalize + transpose: x[b,c,s] -> ht[b*s, c] bf16 ----------------
__global__ __launch_bounds__(256) void gn_apply_t(const float* __restrict__ x,
                                                  const float* __restrict__ gamma,
                                                  const float* __restrict__ beta,
                                                  const float* __restrict__ stats,
                                                  u16* __restrict__ ht) {
  __shared__ float tile[32][33];
  const int b = blockIdx.z, c0 = blockIdx.y * 32, s0 = blockIdx.x * 32;
  const int tx = threadIdx.x, ty = threadIdx.y;
#pragma unroll
  for (int i = 0; i < 4; ++i) {
    const int c  = c0 + ty + i * 8;
    const float mu = stats[(b * G_ + (c >> 4)) * 2];
    const float rs = stats[(b * G_ + (c >> 4)) * 2 + 1];
    const float v  = x[((size_t)b * C_ + c) * S_ + s0 + tx];
    tile[ty + i * 8][tx] = (v - mu) * rs * gamma[c] + beta[c];
  }
  __syncthreads();
#pragma unroll
  for (int i = 0; i < 4; ++i) {
    const int s = s0 + ty + i * 8;
    ht[((size_t)b * S_ + s) * C_ + c0 + tx] = f2bf(tile[tx][ty + i * 8]);
  }
}

// ======= 256x256 8-phase GEMM — single barrier/phase, compiler-counted lgkm =======
// C[m,n] = alpha * sum_k A[m,k]*B[n,k] (+bias[n]); A,B bf16 K-contiguous.
// 512 thr = 8 waves (2M x 4N), strided frags: m-frag f at wm+f*32, n-frag g at
// wn+g*64. LDS As/Bs[2 dbuf][2 half][128][64] u16; swizzle phys granule = g^(row&7).
// Phase = {ds_reads; stage; [counted vmcnt]; BAR; setprio(1) MFMA setprio(0)}.
// NO hard lgkmcnt(0): compiler emits per-fragment counted lgkm waits so MFMA
// starts as soon as its first frags land, and next phase's reads/stages issue
// under the MFMA tail. Counted vmcnt(4) at p3/p7 pre-barrier (asm volatile,
// unhoistable) drains exactly the 8 loads of the dbuf read next; steady state
// 12 loads in flight, never 0.
// ZMODE 1 = PV split-K: bz -> (b = bz>>1, kh = bz&1), hardcoded offsets.
// SMAX 1 = scores epilogue: write exp(alpha*acc) bf16 + per-block row-sum partials.
template <int BIAS_MODE, int ZMODE, int SMAX>
__global__ __launch_bounds__(512, 2) void gemm8p(
    const u16* __restrict__ Ag, int lda, long sA,
    const u16* __restrict__ Bg, int ldb, long sB,
    u16* __restrict__ Cg, int ldc, long sC,
    const float* __restrict__ bias, float alpha, int K,
    float* __restrict__ smx) {
  __shared__ u16 As[2][2][8192];
  __shared__ u16 Bs[2][2][8192];
  __shared__ float ps[4][256];
  int bx, by, bz;
  xcd_swz(bx, by, bz);
  const u16 *A, *Bm;
  u16* Cb;
  if (ZMODE == 0) {
    A = Ag + (size_t)bz * sA; Bm = Bg + (size_t)bz * sB; Cb = Cg + (size_t)bz * sC;
  } else {  // PV split-K: A = P[b], cols kh*2048+; B = V rows, cols b*4096+kh*2048+
    const int b = bz >> 1, kh = bz & 1;
    A  = Ag + (size_t)b * 16777216 + (size_t)kh * 2048;
    Bm = Bg + (size_t)b * 4096 + (size_t)kh * 2048;
    Cb = Cg + (size_t)kh * 8388608 + (size_t)b * 2097152;
  }
  const int bm = by * 256, bn = bx * 256;
  const int tid = threadIdx.x;
  const int wid = tid >> 6, lane = tid & 63;
  const int wm = (wid >> 2) * 16, wn = (wid & 3) * 16;
  const int lr = lane & 15, lh = lane >> 4;
  const int x7 = lr & 7;
  const int g0 = (lh ^ x7) * 8, g1 = ((4 | lh) ^ x7) * 8;  // swizzled granule offs (kh=0/1)

  // staging: wave w covers rows w*8..w*8+7 (+64) of each half; pre-swizzled source
  const int sg = (lane & 7) ^ ((lane >> 3) & 7);
  const u16* Abase = A  + (size_t)(bm + wid * 8 + (lane >> 3)) * lda + sg * 8;
  const u16* Bbase = Bm + (size_t)(bn + wid * 8 + (lane >> 3)) * ldb + sg * 8;

#define STGA(D, H, T) do {                                                   \
    const u16* _s = Abase + (size_t)((H) * 128) * lda + (size_t)(T) * 64;    \
    g2lds16(_s,                    &As[D][H][wid * 512]);                    \
    g2lds16(_s + (size_t)64 * lda, &As[D][H][4096 + wid * 512]);             \
  } while (0)
#define STGB(D, H, T) do {                                                   \
    const u16* _s = Bbase + (size_t)((H) * 128) * ldb + (size_t)(T) * 64;    \
    g2lds16(_s,                    &Bs[D][H][wid * 512]);                    \
    g2lds16(_s + (size_t)64 * ldb, &Bs[D][H][4096 + wid * 512]);             \
  } while (0)

  // bias preload FIRST: its 4 loads are oldest, drained by the prologue vmcnt(4)
  float bias_v[4] = {0.f, 0.f, 0.f, 0.f};
  if (BIAS_MODE == 1) {
#pragma unroll
    for (int g = 0; g < 4; ++g) bias_v[g] = bias[bn + wn + g * 64 + lr];
  }
  SCHED0();

  f32x4 acc[8][4];
  const f32x4 zero = {0.f, 0.f, 0.f, 0.f};
#pragma unroll
  for (int i = 0; i < 8; ++i)
#pragma unroll
    for (int j = 0; j < 4; ++j) acc[i][j] = zero;

  bf16x8 a_[4][2], b_[4][2];

#define RDA(D, AH) do {                                                      \
    _Pragma("unroll") for (int i = 0; i < 4; ++i) {                          \
      const int _o = (wm + i * 32 + lr) * 64;                                \
      a_[i][0] = *(const bf16x8*)&As[D][AH][_o + g0];                        \
      a_[i][1] = *(const bf16x8*)&As[D][AH][_o + g1];                        \
    } } while (0)
#define RDB(D, BH) do {                                                      \
    _Pragma("unroll") for (int j = 0; j < 2; ++j) {                          \
      const int _o = (wn + j * 64 + lr) * 64;                                \
      b_[(BH) * 2 + j][0] = *(const bf16x8*)&Bs[D][BH][_o + g0];             \
      b_[(BH) * 2 + j][1] = *(const bf16x8*)&Bs[D][BH][_o + g1];             \
    } } while (0)
#define MM(AH, BH) do {                                                      \
    __builtin_amdgcn_s_setprio(1);                                           \
    _Pragma("unroll") for (int i = 0; i < 4; ++i)                            \
    _Pragma("unroll") for (int j = 0; j < 2; ++j) {                          \
      acc[(AH) * 4 + i][(BH) * 2 + j] = __builtin_amdgcn_mfma_f32_16x16x32_bf16( \
          a_[i][0], b_[(BH) * 2 + j][0], acc[(AH) * 4 + i][(BH) * 2 + j], 0, 0, 0); \
      acc[(AH) * 4 + i][(BH) * 2 + j] = __builtin_amdgcn_mfma_f32_16x16x32_bf16( \
          a_[i][1], b_[(BH) * 2 + j][1], acc[(AH) * 4 + i][(BH) * 2 + j], 0, 0, 0); \
    }                                                                        \
    __builtin_amdgcn_s_setprio(0);                                           \
  } while (0)

  // prologue: tile0 all 4 halves, then tile1 A0,B1; drain tile0 BEFORE the barrier
  STGA(0, 0, 0); STGB(0, 1, 0); STGA(0, 1, 0); STGB(0, 0, 0);
  STGA(1, 0, 1); STGB(1, 1, 1);
  WAITV4;
  BAR();

  const int nt = K >> 6;  // even, >= 4
  for (int i = 0; i < nt / 2; ++i) {
    const int t1 = 2 * i + 1, t2 = 2 * i + 2, t3 = 2 * i + 3;
    const bool s2 = t2 < nt, s3 = t3 < nt;
    // p0 (d0, A0,B0)
    RDA(0, 0); RDB(0, 0);
    STGB(1, 0, t1);
    BAR(); MM(0, 0);
    // p1 (d0, A0,B1)
    RDB(0, 1);
    STGA(1, 1, t1);
    BAR(); MM(0, 1);
    // p2 (d0, A1,B1)
    RDA(0, 1);
    if (s2) STGA(0, 0, t2);
    BAR(); MM(1, 1);
    // p3 (d0, A1,B0) — counted drain of d1's stages before the phase barrier
    if (s2) STGB(0, 1, t2);
    if (s2) { WAITV4; } else { WAITV0; }
    BAR(); MM(1, 0);
    // p4 (d1, A0,B0)
    RDA(1, 0); RDB(1, 0);
    if (s2) STGA(0, 1, t2);
    BAR(); MM(0, 0);
    // p5 (d1, A0,B1)
    RDB(1, 1);
    if (s2) STGB(0, 0, t2);
    BAR(); MM(0, 1);
    // p6 (d1, A1,B1)
    RDA(1, 1);
    if (s3) STGA(1, 0, t3);
    BAR(); MM(1, 1);
    // p7 (d1, A1,B0) — counted drain of next d0's stages before the phase barrier
    if (s3) STGB(1, 1, t3);
    if (s3) { WAITV4; }
    BAR(); MM(1, 0);
  }
#undef STGA
#undef STGB
#undef RDA
#undef RDB
#undef MM
  SCHED0();

  if (SMAX) {
    // P = exp(alpha*s) bf16 + per-(row, col-block) partial sums -> smx
    float rs[8][4];
#pragma unroll
    for (int f = 0; f < 8; ++f) {
      const int row0 = bm + wm + f * 32 + lh * 4;
#pragma unroll
      for (int r = 0; r < 4; ++r) rs[f][r] = 0.f;
#pragma unroll
      for (int g = 0; g < 4; ++g) {
        const int col = bn + wn + g * 64 + lr;
#pragma unroll
        for (int r = 0; r < 4; ++r) {
          const float e = __expf(acc[f][g][r] * alpha);
          rs[f][r] += e;
          Cb[(size_t)(row0 + r) * ldc + col] = f2bf(e);
        }
      }
#pragma unroll
      for (int r = 0; r < 4; ++r) {
        float v = rs[f][r];
        v += __shfl_xor(v, 1, 64);
        v += __shfl_xor(v, 2, 64);
        v += __shfl_xor(v, 4, 64);
        v += __shfl_xor(v, 8, 64);
        rs[f][r] = v;
      }
    }
    // cross-wave (over wn) reduction: compile-time-predicated LDS writes
#pragma unroll
    for (int f = 0; f < 8; ++f)
#pragma unroll
      for (int r = 0; r < 4; ++r)
        if (lr == ((f << 1) | (r >> 1)))
          ps[wid & 3][wm + f * 32 + lh * 4 + r] = rs[f][r];
    __syncthreads();
    if (tid < 256) {
      const float tot = ps[0][tid] + ps[1][tid] + ps[2][tid] + ps[3][tid];
      smx[((size_t)(bz * 16 + bx) << 12) + bm + tid] = tot;
    }
  } else {
#pragma unroll
    for (int f = 0; f < 8; ++f) {
      const int row0 = bm + wm + f * 32 + lh * 4;
#pragma unroll
      for (int g = 0; g < 4; ++g) {
        const int col = bn + wn + g * 64 + lr;
#pragma unroll
        for (int r = 0; r < 4; ++r)
          Cb[(size_t)(row0 + r) * ldc + col] = f2bf(acc[f][g][r] * alpha + bias_v[g]);
      }
    }
  }
}

// ---------------- 128x128 GEMM (V-proj and out-proj) ----------------
// BCOMB=1: B-operand is the fp32 sum of two bf16 psum buffers (Bg, Bg2), added
// during reg-staged B-staging (replaces the separate add_scale pass).
// OUT_MODE=1: fp32 out[b,o,s] = acc*lscale[n] + bias[m] + xres, n = b*S+s.
#define GBM 128
#define GBN 128
#define GBK 64

template <int BIAS_MODE, int OUT_MODE, int BCOMB>
__global__ __launch_bounds__(256) void gemm_abT(
    const u16* __restrict__ Ag, int lda, long sA,
    const u16* __restrict__ Bg, int ldb, long sB,
    void* __restrict__ Cg, int ldc, long sC,
    const float* __restrict__ bias, float alpha,
    const float* __restrict__ xres, const float* __restrict__ lscale,
    const u16* __restrict__ Bg2, int K) {
  __shared__ u16 As[GBM * GBK];
  __shared__ u16 Bs[GBN * GBK];
  const int bz = blockIdx.z;
  const u16* A    = Ag + (size_t)bz * sA;
  const u16* Bmat = Bg + (size_t)bz * sB;
  const int bm = blockIdx.y * GBM, bn = blockIdx.x * GBN;
  const int tid = threadIdx.x;
  const int wid = tid >> 6, lane = tid & 63;
  const int wm = (wid >> 1) * 64, wn = (wid & 1) * 64;
  const int lr = lane & 15, lh = lane >> 4;
  const int srow = lane >> 3, scol = (lane & 7) * 8;

  f32x4 acc[4][4];
  const f32x4 zero = {0.f, 0.f, 0.f, 0.f};
#pragma unroll
  for (int i = 0; i < 4; ++i)
#pragma unroll
    for (int j = 0; j < 4; ++j) acc[i][j] = zero;

  for (int k0 = 0; k0 < K; k0 += GBK) {
    __syncthreads();
#pragma unroll
    for (int i = 0; i < 4; ++i) {
      const int chunk = wid * 4 + i;
      const int row   = chunk * 8 + srow;
      g2lds16(A + (size_t)(bm + row) * lda + (k0 + scol), &As[chunk * 512]);
      if (BCOMB == 0) {
        g2lds16(Bmat + (size_t)(bn + row) * ldb + (k0 + scol), &Bs[chunk * 512]);
      } else {
        const size_t boff = (size_t)(bn + row) * ldb + (k0 + scol);
        const uint4 u0 = *(const uint4*)(Bmat + boff);
        const uint4 u1 = *(const uint4*)(Bg2 + boff);
        const unsigned* p0 = (const unsigned*)&u0;
        const unsigned* p1 = (const unsigned*)&u1;
        unsigned rr[4];
#pragma unroll
        for (int k = 0; k < 4; ++k) {
          const float lo = bf2f((u16)(p0[k] & 0xffffu)) + bf2f((u16)(p1[k] & 0xffffu));
          const float hi = bf2f((u16)(p0[k] >> 16)) + bf2f((u16)(p1[k] >> 16));
          rr[k] = (unsigned)f2bf(lo) | ((unsigned)f2bf(hi) << 16);
        }
        *(uint4*)&Bs[chunk * 512 + lane * 8] = *(const uint4*)rr;
      }
    }
    __syncthreads();
#pragma unroll
    for (int ks = 0; ks < 2; ++ks) {
      bf16x8 a_[4], b_[4];
#pragma unroll
      for (int m = 0; m < 4; ++m)
        a_[m] = *(const bf16x8*)&As[(wm + m * 16 + lr) * GBK + ks * 32 + lh * 8];
#pragma unroll
      for (int n = 0; n < 4; ++n)
        b_[n] = *(const bf16x8*)&Bs[(wn + n * 16 + lr) * GBK + ks * 32 + lh * 8];
#pragma unroll
      for (int m = 0; m < 4; ++m)
#pragma unroll
        for (int n = 0; n < 4; ++n)
          acc[m][n] = __builtin_amdgcn_mfma_f32_16x16x32_bf16(a_[m], b_[n], acc[m][n], 0, 0, 0);
    }
  }

  if (OUT_MODE == 0) {
    u16* Cb = (u16*)Cg + (size_t)bz * sC;
#pragma unroll
    for (int m = 0; m < 4; ++m) {
      const int row0 = bm + wm + m * 16 + lh * 4;
#pragma unroll
      for (int n = 0; n < 4; ++n) {
        const int col = bn + wn + n * 16 + lr;
        float bn_ = (BIAS_MODE == 1) ? bias[col] : 0.f;
#pragma unroll
        for (int r = 0; r < 4; ++r) {
          float bb = (BIAS_MODE == 2) ? bias[row0 + r] : bn_;
          Cb[(size_t)(row0 + r) * ldc + col] = f2bf(acc[m][n][r] * alpha + bb);
        }
      }
    }
  } else {
    float* Ob = (float*)Cg;
#pragma unroll
    for (int m = 0; m < 4; ++m) {
      const int row0 = bm + wm + m * 16 + lh * 4;
#pragma unroll
      for (int n = 0; n < 4; ++n) {
        const int col = bn + wn + n * 16 + lr;
        const int bb = col >> 12, sp = col & (S_ - 1);
        const float lsc = lscale[col];
#pragma unroll
        for (int r = 0; r < 4; ++r) {
          const int o = row0 + r;
          const size_t idx = ((size_t)bb * C_ + o) * S_ + sp;
          Ob[idx] = acc[m][n][r] * lsc + bias[o] + xres[idx];
        }
      }
    }
  }
}

extern "C" void kernel_launch(void* const* d_in, const int* in_sizes, int n_in,
                              void* d_out, int out_size, void* d_ws, size_t ws_size,
                              hipStream_t stream) {
  const float* x     = (const float*)d_in[0];
  const float* gamma = (const float*)d_in[1];
  const float* beta  = (const float*)d_in[2];
  const float* wq = (const float*)d_in[3];
  const float* bq = (const float*)d_in[4];
  const float* wk = (const float*)d_in[5];
  const float* bk = (const float*)d_in[6];
  const float* wv = (const float*)d_in[7];
  const float* bv = (const float*)d_in[8];
  const float* wo = (const float*)d_in[9];
  const float* bo = (const float*)d_in[10];
  float* out = (float*)d_out;

  // ws: stats 1KB | weights bf16 4x512KB | bqk 4KB | ht 16MB | qkt 32MB | vv 16MB
  //     | sc 128MB | partials 1MB | Lr 64KB
  char* ws = (char*)d_ws;
  float* stats = (float*)ws;
  u16* wqb = (u16*)(ws + 1024);
  u16* wkb = wqb + 262144;   // contiguous after wqb -> [wq;wk] is one 1024x512 matrix
  u16* wvb = wkb + 262144;
  u16* wob = wvb + 262144;
  float* bqk = (float*)(wob + 262144);
  u16* ht  = (u16*)((char*)bqk + 4096);  // [B*S, C]
  u16* qkt = ht + 8388608;               // [B*S, 1024] (q|k); later PV psum halves
  u16* vv  = qkt + 16777216;             // [C, B*S]
  u16* sc  = vv + 8388608;               // [B, S, S] exp(scores)
  float* partials = (float*)(sc + 67108864);  // [B][16][4096]
  float* Lr = partials + 262144;              // [B][4096]

  f32_to_bf16<<<1024, 256, 0, stream>>>(wq, wqb, 262144);
  f32_to_bf16<<<1024, 256, 0, stream>>>(wk, wkb, 262144);
  f32_to_bf16<<<1024, 256, 0, stream>>>(wv, wvb, 262144);
  f32_to_bf16<<<1024, 256, 0, stream>>>(wo, wob, 262144);
  concat_bias<<<4, 256, 0, stream>>>(bq, bk, bqk);

  gn_stats<<<128, 256, 0, stream>>>(x, stats);
  gn_apply_t<<<dim3(128, 16, 4), dim3(32, 8), 0, stream>>>(x, gamma, beta, stats, ht);

  // fused Q|K projection: qkt[bs, 0:512]=Q, [512:1024]=K   (256 blocks)
  gemm8p<1, 0, 0><<<dim3(4, 64, 1), 512, 0, stream>>>(ht, 512, 0, wqb, 512, 0,
                                                      qkt, 1024, 0, bqk, 1.f, 512, nullptr);
  // V[c, b*S+s]: bias per m (=c)                            (512 blocks)
  gemm_abT<2, 0, 0><<<dim3(128, 4, 1), 256, 0, stream>>>(wvb, 512, 0, ht, 512, 0,
                                                         vv, 16384, 0, bv, 1.f,
                                                         nullptr, nullptr, nullptr, 512);
  // P[b,i,j] = exp(scale * Q.K) + row-sum partials          (1024 blocks)
  gemm8p<0, 0, 1><<<dim3(16, 16, 4), 512, 0, stream>>>(qkt, 1024, 4194304, qkt + 512, 1024, 4194304,
                                                       sc, 4096, 16777216, nullptr,
                                                       0.04419417382415922f, 512, partials);
  reduce_l<<<64, 256, 0, stream>>>(partials, Lr);
  // PV split-K=2 on unnormalized P: psums in qkt halves     (256 blocks)
  gemm8p<0, 1, 0><<<dim3(2, 16, 8), 512, 0, stream>>>(sc, 4096, 0, vv, 16384, 0,
                                                      qkt, 512, 0, nullptr, 1.f, 2048, nullptr);
  // out[b,o,s] = (Wo @ (psum0+psum1)) * Lr[bs] + bo + x      (512 blocks)
  gemm_abT<2, 1, 1><<<dim3(128, 4, 1), 256, 0, stream>>>(wob, 512, 0, qkt, 512, 0,
                                                         out, 0, 0, bo, 1.f,
                                                         x, Lr, qkt + 8388608, 512);
}

// Round 17
// 278.980 us; speedup vs baseline: 1.1742x; 1.0236x over previous
//
#include <hip/hip_runtime.h>

#define B_   4
#define C_   512
#define S_   4096
#define G_   32
#define CPG_ 16
#define EPS_ 1e-6f

typedef unsigned short u16;
typedef __bf16 bf16x8 __attribute__((ext_vector_type(8)));
typedef float  f32x4  __attribute__((ext_vector_type(4)));

__device__ __forceinline__ u16 f2bf(float f) {
  unsigned u = __float_as_uint(f);
  u += 0x7fffu + ((u >> 16) & 1u);   // RNE
  return (u16)(u >> 16);
}
__device__ __forceinline__ float bf2f(u16 h) {
  return __uint_as_float((unsigned)h << 16);
}

__device__ __forceinline__ void g2lds16(const void* g, void* l) {
  __builtin_amdgcn_global_load_lds(
      (const __attribute__((address_space(1))) void*)g,
      (__attribute__((address_space(3))) void*)l, 16, 0, 0);
}

#define BAR()    __builtin_amdgcn_s_barrier()
#define SCHED0() __builtin_amdgcn_sched_barrier(0)
#define WAITV4   asm volatile("s_waitcnt vmcnt(4)" ::: "memory")
#define WAITV0   asm volatile("s_waitcnt vmcnt(0)" ::: "memory")

// chunked XCD swizzle (bijective when nwg % 8 == 0 — all grids here satisfy it)
__device__ __forceinline__ void xcd_swz(int& bx, int& by, int& bz) {
  const int gx = gridDim.x, gy = gridDim.y;
  const int nwg = gx * gy * (int)gridDim.z;
  const int flat = blockIdx.x + gx * (blockIdx.y + gy * blockIdx.z);
  const int q = nwg >> 3;
  const int nf = (flat & 7) * q + (flat >> 3);
  bx = nf % gx;
  const int r = nf / gx;
  by = r % gy;
  bz = r / gy;
}

// ---- fused prep: 4x fp32->bf16 weight conversion + bias concat, one dispatch ----
// wout = contiguous [wq|wk|wv|wo] bf16 region (4 x 262144).
__global__ __launch_bounds__(256) void prep(const float* __restrict__ wq,
                                            const float* __restrict__ wk,
                                            const float* __restrict__ wv,
                                            const float* __restrict__ wo,
                                            const float* __restrict__ bq,
                                            const float* __restrict__ bk,
                                            u16* __restrict__ wout,
                                            float* __restrict__ bqk) {
  const int bid = blockIdx.x;
  const int tid = threadIdx.x;
  if (bid < 4096) {
    const int i = bid * 256 + tid;          // 0..1048575
    const int sel = i >> 18;                // which weight matrix
    const int off = i & 262143;
    const float* src = (sel == 0) ? wq : (sel == 1) ? wk : (sel == 2) ? wv : wo;
    wout[i] = f2bf(src[off]);
  } else {
    const int i = (bid - 4096) * 256 + tid; // 0..1023
    bqk[i] = (i < 512) ? bq[i] : bk[i - 512];
  }
}

// ---------------- softmax denominator: Lr[b,i] = 1/sum_jb partial ----------------
__global__ __launch_bounds__(256) void reduce_l(const float* __restrict__ p,
                                                float* __restrict__ lr) {
  const int i = blockIdx.x * 256 + threadIdx.x;   // 16384 = B*S
  const int b = i >> 12, row = i & 4095;
  float s = 0.f;
#pragma unroll
  for (int jb = 0; jb < 16; ++jb) s += p[((size_t)(b * 16 + jb) << 12) + row];
  lr[i] = 1.f / s;
}

// ---------------- GroupNorm stats: one block per (b,g) ----------------
__global__ __launch_bounds__(256) void gn_stats(const float* __restrict__ x,
                                                float* __restrict__ stats) {
  const int bg = blockIdx.x;
  const float4* p4 = (const float4*)(x + (size_t)bg * (CPG_ * S_));
  float s = 0.f, ss = 0.f;
  const int tid = threadIdx.x;
  for (int i = tid; i < CPG_ * S_ / 4; i += 256) {
    float4 v = p4[i];
    s  += v.x + v.y + v.z + v.w;
    ss += v.x * v.x + v.y * v.y + v.z * v.z + v.w * v.w;
  }
#pragma unroll
  for (int o = 32; o; o >>= 1) { s += __shfl_xor(s, o, 64); ss += __shfl_xor(ss, o, 64); }
  __shared__ float sm[8];
  const int wid = tid >> 6, lane = tid & 63;
  if (lane == 0) { sm[wid * 2] = s; sm[wid * 2 + 1] = ss; }
  __syncthreads();
  if (tid == 0) {
    s  = sm[0] + sm[2] + sm[4] + sm[6];
    ss = sm[1] + sm[3] + sm[5] + sm[7];
    const float inv = 1.f / (float)(CPG_ * S_);
    float mu = s * inv;
    float var = ss * inv - mu * mu;
    stats[bg * 2]     = mu;
    stats[bg * 2 + 1] = rsqrtf(var + EPS_);
  }
}

// ---------------- normalize + transpose: x[b,c,s] -> ht[b*s, c] bf16 ----------------
__global__ __launch_bounds__(256) void gn_apply_t(const float* __restrict__ x,
                                                  const float* __restrict__ gamma,
                                                  const float* __restrict__ beta,
                                                  const float* __restrict__ stats,
                                                  u16* __restrict__ ht) {
  __shared__ float tile[32][33];
  const int b = blockIdx.z, c0 = blockIdx.y * 32, s0 = blockIdx.x * 32;
  const int tx = threadIdx.x, ty = threadIdx.y;
#pragma unroll
  for (int i = 0; i < 4; ++i) {
    const int c  = c0 + ty + i * 8;
    const float mu = stats[(b * G_ + (c >> 4)) * 2];
    const float rs = stats[(b * G_ + (c >> 4)) * 2 + 1];
    const float v  = x[((size_t)b * C_ + c) * S_ + s0 + tx];
    tile[ty + i * 8][tx] = (v - mu) * rs * gamma[c] + beta[c];
  }
  __syncthreads();
#pragma unroll
  for (int i = 0; i < 4; ++i) {
    const int s = s0 + ty + i * 8;
    ht[((size_t)b * S_ + s) * C_ + c0 + tx] = f2bf(tile[tx][ty + i * 8]);
  }
}

// ======= 256x256 8-phase GEMM — single barrier/phase, compiler-counted lgkm =======
// C[m,n] = alpha * sum_k A[m,k]*B[n,k] (+bias[n]); A,B bf16 K-contiguous.
// 512 thr = 8 waves (2M x 4N), strided frags: m-frag f at wm+f*32, n-frag g at
// wn+g*64. LDS As/Bs[2 dbuf][2 half][128][64] u16; swizzle phys granule = g^(row&7).
// Phase = {ds_reads; stage; [counted vmcnt]; BAR; setprio(1) MFMA setprio(0)}.
// NO hard lgkmcnt(0): compiler emits per-fragment counted lgkm waits so MFMA
// starts as soon as its first frags land, and next phase's reads/stages issue
// under the MFMA tail. Counted vmcnt(4) at p3/p7 pre-barrier (asm volatile,
// unhoistable) drains exactly the 8 loads of the dbuf read next; steady state
// 12 loads in flight, never 0.
// ZMODE 1 = PV split-K: bz -> (b = bz>>1, kh = bz&1), hardcoded offsets.
// SMAX 1 = scores epilogue: write exp(alpha*acc) bf16 + per-block row-sum partials.
template <int BIAS_MODE, int ZMODE, int SMAX>
__global__ __launch_bounds__(512, 2) void gemm8p(
    const u16* __restrict__ Ag, int lda, long sA,
    const u16* __restrict__ Bg, int ldb, long sB,
    u16* __restrict__ Cg, int ldc, long sC,
    const float* __restrict__ bias, float alpha, int K,
    float* __restrict__ smx) {
  __shared__ u16 As[2][2][8192];
  __shared__ u16 Bs[2][2][8192];
  __shared__ float ps[4][256];
  int bx, by, bz;
  xcd_swz(bx, by, bz);
  const u16 *A, *Bm;
  u16* Cb;
  if (ZMODE == 0) {
    A = Ag + (size_t)bz * sA; Bm = Bg + (size_t)bz * sB; Cb = Cg + (size_t)bz * sC;
  } else {  // PV split-K: A = P[b], cols kh*2048+; B = V rows, cols b*4096+kh*2048+
    const int b = bz >> 1, kh = bz & 1;
    A  = Ag + (size_t)b * 16777216 + (size_t)kh * 2048;
    Bm = Bg + (size_t)b * 4096 + (size_t)kh * 2048;
    Cb = Cg + (size_t)kh * 8388608 + (size_t)b * 2097152;
  }
  const int bm = by * 256, bn = bx * 256;
  const int tid = threadIdx.x;
  const int wid = tid >> 6, lane = tid & 63;
  const int wm = (wid >> 2) * 16, wn = (wid & 3) * 16;
  const int lr = lane & 15, lh = lane >> 4;
  const int x7 = lr & 7;
  const int g0 = (lh ^ x7) * 8, g1 = ((4 | lh) ^ x7) * 8;  // swizzled granule offs (kh=0/1)

  // staging: wave w covers rows w*8..w*8+7 (+64) of each half; pre-swizzled source
  const int sg = (lane & 7) ^ ((lane >> 3) & 7);
  const u16* Abase = A  + (size_t)(bm + wid * 8 + (lane >> 3)) * lda + sg * 8;
  const u16* Bbase = Bm + (size_t)(bn + wid * 8 + (lane >> 3)) * ldb + sg * 8;

#define STGA(D, H, T) do {                                                   \
    const u16* _s = Abase + (size_t)((H) * 128) * lda + (size_t)(T) * 64;    \
    g2lds16(_s,                    &As[D][H][wid * 512]);                    \
    g2lds16(_s + (size_t)64 * lda, &As[D][H][4096 + wid * 512]);             \
  } while (0)
#define STGB(D, H, T) do {                                                   \
    const u16* _s = Bbase + (size_t)((H) * 128) * ldb + (size_t)(T) * 64;    \
    g2lds16(_s,                    &Bs[D][H][wid * 512]);                    \
    g2lds16(_s + (size_t)64 * ldb, &Bs[D][H][4096 + wid * 512]);             \
  } while (0)

  // bias preload FIRST: its 4 loads are oldest, drained by the prologue vmcnt(4)
  float bias_v[4] = {0.f, 0.f, 0.f, 0.f};
  if (BIAS_MODE == 1) {
#pragma unroll
    for (int g = 0; g < 4; ++g) bias_v[g] = bias[bn + wn + g * 64 + lr];
  }
  SCHED0();

  f32x4 acc[8][4];
  const f32x4 zero = {0.f, 0.f, 0.f, 0.f};
#pragma unroll
  for (int i = 0; i < 8; ++i)
#pragma unroll
    for (int j = 0; j < 4; ++j) acc[i][j] = zero;

  bf16x8 a_[4][2], b_[4][2];

#define RDA(D, AH) do {                                                      \
    _Pragma("unroll") for (int i = 0; i < 4; ++i) {                          \
      const int _o = (wm + i * 32 + lr) * 64;                                \
      a_[i][0] = *(const bf16x8*)&As[D][AH][_o + g0];                        \
      a_[i][1] = *(const bf16x8*)&As[D][AH][_o + g1];                        \
    } } while (0)
#define RDB(D, BH) do {                                                      \
    _Pragma("unroll") for (int j = 0; j < 2; ++j) {                          \
      const int _o = (wn + j * 64 + lr) * 64;                                \
      b_[(BH) * 2 + j][0] = *(const bf16x8*)&Bs[D][BH][_o + g0];             \
      b_[(BH) * 2 + j][1] = *(const bf16x8*)&Bs[D][BH][_o + g1];             \
    } } while (0)
#define MM(AH, BH) do {                                                      \
    __builtin_amdgcn_s_setprio(1);                                           \
    _Pragma("unroll") for (int i = 0; i < 4; ++i)                            \
    _Pragma("unroll") for (int j = 0; j < 2; ++j) {                          \
      acc[(AH) * 4 + i][(BH) * 2 + j] = __builtin_amdgcn_mfma_f32_16x16x32_bf16( \
          a_[i][0], b_[(BH) * 2 + j][0], acc[(AH) * 4 + i][(BH) * 2 + j], 0, 0, 0); \
      acc[(AH) * 4 + i][(BH) * 2 + j] = __builtin_amdgcn_mfma_f32_16x16x32_bf16( \
          a_[i][1], b_[(BH) * 2 + j][1], acc[(AH) * 4 + i][(BH) * 2 + j], 0, 0, 0); \
    }                                                                        \
    __builtin_amdgcn_s_setprio(0);                                           \
  } while (0)

  // prologue: tile0 all 4 halves, then tile1 A0,B1; drain tile0 BEFORE the barrier
  STGA(0, 0, 0); STGB(0, 1, 0); STGA(0, 1, 0); STGB(0, 0, 0);
  STGA(1, 0, 1); STGB(1, 1, 1);
  WAITV4;
  BAR();

  const int nt = K >> 6;  // even, >= 4
  for (int i = 0; i < nt / 2; ++i) {
    const int t1 = 2 * i + 1, t2 = 2 * i + 2, t3 = 2 * i + 3;
    const bool s2 = t2 < nt, s3 = t3 < nt;
    // p0 (d0, A0,B0)
    RDA(0, 0); RDB(0, 0);
    STGB(1, 0, t1);
    BAR(); MM(0, 0);
    // p1 (d0, A0,B1)
    RDB(0, 1);
    STGA(1, 1, t1);
    BAR(); MM(0, 1);
    // p2 (d0, A1,B1)
    RDA(0, 1);
    if (s2) STGA(0, 0, t2);
    BAR(); MM(1, 1);
    // p3 (d0, A1,B0) — counted drain of d1's stages before the phase barrier
    if (s2) STGB(0, 1, t2);
    if (s2) { WAITV4; } else { WAITV0; }
    BAR(); MM(1, 0);
    // p4 (d1, A0,B0)
    RDA(1, 0); RDB(1, 0);
    if (s2) STGA(0, 1, t2);
    BAR(); MM(0, 0);
    // p5 (d1, A0,B1)
    RDB(1, 1);
    if (s2) STGB(0, 0, t2);
    BAR(); MM(0, 1);
    // p6 (d1, A1,B1)
    RDA(1, 1);
    if (s3) STGA(1, 0, t3);
    BAR(); MM(1, 1);
    // p7 (d1, A1,B0) — counted drain of next d0's stages before the phase barrier
    if (s3) STGB(1, 1, t3);
    if (s3) { WAITV4; }
    BAR(); MM(1, 0);
  }
#undef STGA
#undef STGB
#undef RDA
#undef RDB
#undef MM
  SCHED0();

  if (SMAX) {
    // P = exp(alpha*s) bf16 + per-(row, col-block) partial sums -> smx
    float rs[8][4];
#pragma unroll
    for (int f = 0; f < 8; ++f) {
      const int row0 = bm + wm + f * 32 + lh * 4;
#pragma unroll
      for (int r = 0; r < 4; ++r) rs[f][r] = 0.f;
#pragma unroll
      for (int g = 0; g < 4; ++g) {
        const int col = bn + wn + g * 64 + lr;
#pragma unroll
        for (int r = 0; r < 4; ++r) {
          const float e = __expf(acc[f][g][r] * alpha);
          rs[f][r] += e;
          Cb[(size_t)(row0 + r) * ldc + col] = f2bf(e);
        }
      }
#pragma unroll
      for (int r = 0; r < 4; ++r) {
        float v = rs[f][r];
        v += __shfl_xor(v, 1, 64);
        v += __shfl_xor(v, 2, 64);
        v += __shfl_xor(v, 4, 64);
        v += __shfl_xor(v, 8, 64);
        rs[f][r] = v;
      }
    }
    // cross-wave (over wn) reduction: compile-time-predicated LDS writes
#pragma unroll
    for (int f = 0; f < 8; ++f)
#pragma unroll
      for (int r = 0; r < 4; ++r)
        if (lr == ((f << 1) | (r >> 1)))
          ps[wid & 3][wm + f * 32 + lh * 4 + r] = rs[f][r];
    __syncthreads();
    if (tid < 256) {
      const float tot = ps[0][tid] + ps[1][tid] + ps[2][tid] + ps[3][tid];
      smx[((size_t)(bz * 16 + bx) << 12) + bm + tid] = tot;
    }
  } else {
#pragma unroll
    for (int f = 0; f < 8; ++f) {
      const int row0 = bm + wm + f * 32 + lh * 4;
#pragma unroll
      for (int g = 0; g < 4; ++g) {
        const int col = bn + wn + g * 64 + lr;
#pragma unroll
        for (int r = 0; r < 4; ++r)
          Cb[(size_t)(row0 + r) * ldc + col] = f2bf(acc[f][g][r] * alpha + bias_v[g]);
      }
    }
  }
}

// ---------------- 128x128 GEMM (V-proj and out-proj) ----------------
// BCOMB=1: B-operand is the fp32 sum of two bf16 psum buffers (Bg, Bg2), added
// during reg-staged B-staging (replaces the separate add_scale pass).
// OUT_MODE=1: fp32 out[b,o,s] = acc*lscale[n] + bias[m] + xres, n = b*S+s.
#define GBM 128
#define GBN 128
#define GBK 64

template <int BIAS_MODE, int OUT_MODE, int BCOMB>
__global__ __launch_bounds__(256) void gemm_abT(
    const u16* __restrict__ Ag, int lda, long sA,
    const u16* __restrict__ Bg, int ldb, long sB,
    void* __restrict__ Cg, int ldc, long sC,
    const float* __restrict__ bias, float alpha,
    const float* __restrict__ xres, const float* __restrict__ lscale,
    const u16* __restrict__ Bg2, int K) {
  __shared__ u16 As[GBM * GBK];
  __shared__ u16 Bs[GBN * GBK];
  const int bz = blockIdx.z;
  const u16* A    = Ag + (size_t)bz * sA;
  const u16* Bmat = Bg + (size_t)bz * sB;
  const int bm = blockIdx.y * GBM, bn = blockIdx.x * GBN;
  const int tid = threadIdx.x;
  const int wid = tid >> 6, lane = tid & 63;
  const int wm = (wid >> 1) * 64, wn = (wid & 1) * 64;
  const int lr = lane & 15, lh = lane >> 4;
  const int srow = lane >> 3, scol = (lane & 7) * 8;

  f32x4 acc[4][4];
  const f32x4 zero = {0.f, 0.f, 0.f, 0.f};
#pragma unroll
  for (int i = 0; i < 4; ++i)
#pragma unroll
    for (int j = 0; j < 4; ++j) acc[i][j] = zero;

  for (int k0 = 0; k0 < K; k0 += GBK) {
    __syncthreads();
#pragma unroll
    for (int i = 0; i < 4; ++i) {
      const int chunk = wid * 4 + i;
      const int row   = chunk * 8 + srow;
      g2lds16(A + (size_t)(bm + row) * lda + (k0 + scol), &As[chunk * 512]);
      if (BCOMB == 0) {
        g2lds16(Bmat + (size_t)(bn + row) * ldb + (k0 + scol), &Bs[chunk * 512]);
      } else {
        const size_t boff = (size_t)(bn + row) * ldb + (k0 + scol);
        const uint4 u0 = *(const uint4*)(Bmat + boff);
        const uint4 u1 = *(const uint4*)(Bg2 + boff);
        const unsigned* p0 = (const unsigned*)&u0;
        const unsigned* p1 = (const unsigned*)&u1;
        unsigned rr[4];
#pragma unroll
        for (int k = 0; k < 4; ++k) {
          const float lo = bf2f((u16)(p0[k] & 0xffffu)) + bf2f((u16)(p1[k] & 0xffffu));
          const float hi = bf2f((u16)(p0[k] >> 16)) + bf2f((u16)(p1[k] >> 16));
          rr[k] = (unsigned)f2bf(lo) | ((unsigned)f2bf(hi) << 16);
        }
        *(uint4*)&Bs[chunk * 512 + lane * 8] = *(const uint4*)rr;
      }
    }
    __syncthreads();
#pragma unroll
    for (int ks = 0; ks < 2; ++ks) {
      bf16x8 a_[4], b_[4];
#pragma unroll
      for (int m = 0; m < 4; ++m)
        a_[m] = *(const bf16x8*)&As[(wm + m * 16 + lr) * GBK + ks * 32 + lh * 8];
#pragma unroll
      for (int n = 0; n < 4; ++n)
        b_[n] = *(const bf16x8*)&Bs[(wn + n * 16 + lr) * GBK + ks * 32 + lh * 8];
#pragma unroll
      for (int m = 0; m < 4; ++m)
#pragma unroll
        for (int n = 0; n < 4; ++n)
          acc[m][n] = __builtin_amdgcn_mfma_f32_16x16x32_bf16(a_[m], b_[n], acc[m][n], 0, 0, 0);
    }
  }

  if (OUT_MODE == 0) {
    u16* Cb = (u16*)Cg + (size_t)bz * sC;
#pragma unroll
    for (int m = 0; m < 4; ++m) {
      const int row0 = bm + wm + m * 16 + lh * 4;
#pragma unroll
      for (int n = 0; n < 4; ++n) {
        const int col = bn + wn + n * 16 + lr;
        float bn_ = (BIAS_MODE == 1) ? bias[col] : 0.f;
#pragma unroll
        for (int r = 0; r < 4; ++r) {
          float bb = (BIAS_MODE == 2) ? bias[row0 + r] : bn_;
          Cb[(size_t)(row0 + r) * ldc + col] = f2bf(acc[m][n][r] * alpha + bb);
        }
      }
    }
  } else {
    float* Ob = (float*)Cg;
#pragma unroll
    for (int m = 0; m < 4; ++m) {
      const int row0 = bm + wm + m * 16 + lh * 4;
#pragma unroll
      for (int n = 0; n < 4; ++n) {
        const int col = bn + wn + n * 16 + lr;
        const int bb = col >> 12, sp = col & (S_ - 1);
        const float lsc = lscale[col];
#pragma unroll
        for (int r = 0; r < 4; ++r) {
          const int o = row0 + r;
          const size_t idx = ((size_t)bb * C_ + o) * S_ + sp;
          Ob[idx] = acc[m][n][r] * lsc + bias[o] + xres[idx];
        }
      }
    }
  }
}

extern "C" void kernel_launch(void* const* d_in, const int* in_sizes, int n_in,
                              void* d_out, int out_size, void* d_ws, size_t ws_size,
                              hipStream_t stream) {
  const float* x     = (const float*)d_in[0];
  const float* gamma = (const float*)d_in[1];
  const float* beta  = (const float*)d_in[2];
  const float* wq = (const float*)d_in[3];
  const float* bq = (const float*)d_in[4];
  const float* wk = (const float*)d_in[5];
  const float* bk = (const float*)d_in[6];
  const float* wv = (const float*)d_in[7];
  const float* bv = (const float*)d_in[8];
  const float* wo = (const float*)d_in[9];
  const float* bo = (const float*)d_in[10];
  float* out = (float*)d_out;

  // ws: stats 1KB | weights bf16 4x512KB | bqk 4KB | ht 16MB | qkt 32MB | vv 16MB
  //     | sc 128MB | partials 1MB | Lr 64KB
  char* ws = (char*)d_ws;
  float* stats = (float*)ws;
  u16* wqb = (u16*)(ws + 1024);
  u16* wkb = wqb + 262144;   // contiguous after wqb -> [wq;wk] is one 1024x512 matrix
  u16* wvb = wkb + 262144;
  u16* wob = wvb + 262144;
  float* bqk = (float*)(wob + 262144);
  u16* ht  = (u16*)((char*)bqk + 4096);  // [B*S, C]
  u16* qkt = ht + 8388608;               // [B*S, 1024] (q|k); later PV psum halves
  u16* vv  = qkt + 16777216;             // [C, B*S]
  u16* sc  = vv + 8388608;               // [B, S, S] exp(scores)
  float* partials = (float*)(sc + 67108864);  // [B][16][4096]
  float* Lr = partials + 262144;              // [B][4096]

  // fused weight-convert + bias-concat (replaces 5 tiny dispatches)
  prep<<<4100, 256, 0, stream>>>(wq, wk, wv, wo, bq, bk, wqb, bqk);

  gn_stats<<<128, 256, 0, stream>>>(x, stats);
  gn_apply_t<<<dim3(128, 16, 4), dim3(32, 8), 0, stream>>>(x, gamma, beta, stats, ht);

  // fused Q|K projection: qkt[bs, 0:512]=Q, [512:1024]=K   (256 blocks)
  gemm8p<1, 0, 0><<<dim3(4, 64, 1), 512, 0, stream>>>(ht, 512, 0, wqb, 512, 0,
                                                      qkt, 1024, 0, bqk, 1.f, 512, nullptr);
  // V[c, b*S+s]: bias per m (=c)                            (512 blocks)
  gemm_abT<2, 0, 0><<<dim3(128, 4, 1), 256, 0, stream>>>(wvb, 512, 0, ht, 512, 0,
                                                         vv, 16384, 0, bv, 1.f,
                                                         nullptr, nullptr, nullptr, 512);
  // P[b,i,j] = exp(scale * Q.K) + row-sum partials          (1024 blocks)
  gemm8p<0, 0, 1><<<dim3(16, 16, 4), 512, 0, stream>>>(qkt, 1024, 4194304, qkt + 512, 1024, 4194304,
                                                       sc, 4096, 16777216, nullptr,
                                                       0.04419417382415922f, 512, partials);
  reduce_l<<<64, 256, 0, stream>>>(partials, Lr);
  // PV split-K=2 on unnormalized P: psums in qkt halves     (256 blocks)
  gemm8p<0, 1, 0><<<dim3(2, 16, 8), 512, 0, stream>>>(sc, 4096, 0, vv, 16384, 0,
                                                      qkt, 512, 0, nullptr, 1.f, 2048, nullptr);
  // out[b,o,s] = (Wo @ (psum0+psum1)) * Lr[bs] + bo + x      (512 blocks)
  gemm_abT<2, 1, 1><<<dim3(128, 4, 1), 256, 0, stream>>>(wob, 512, 0, qkt, 512, 0,
                                                         out, 0, 0, bo, 1.f,
                                                         x, Lr, qkt + 8388608, 512);
}

// Round 18
// 268.590 us; speedup vs baseline: 1.2197x; 1.0387x over previous
//
#include <hip/hip_runtime.h>

#define B_   4
#define C_   512
#define S_   4096
#define G_   32
#define CPG_ 16
#define EPS_ 1e-6f

typedef unsigned short u16;
typedef __bf16 bf16x8 __attribute__((ext_vector_type(8)));
typedef float  f32x4  __attribute__((ext_vector_type(4)));

__device__ __forceinline__ u16 f2bf(float f) {
  unsigned u = __float_as_uint(f);
  u += 0x7fffu + ((u >> 16) & 1u);   // RNE
  return (u16)(u >> 16);
}
__device__ __forceinline__ float bf2f(u16 h) {
  return __uint_as_float((unsigned)h << 16);
}

__device__ __forceinline__ void g2lds16(const void* g, void* l) {
  __builtin_amdgcn_global_load_lds(
      (const __attribute__((address_space(1))) void*)g,
      (__attribute__((address_space(3))) void*)l, 16, 0, 0);
}

#define BAR()    __builtin_amdgcn_s_barrier()
#define SCHED0() __builtin_amdgcn_sched_barrier(0)
#define WAITV4   asm volatile("s_waitcnt vmcnt(4)" ::: "memory")
#define WAITV0   asm volatile("s_waitcnt vmcnt(0)" ::: "memory")

// chunked XCD swizzle (bijective when nwg % 8 == 0 — all grids here satisfy it)
__device__ __forceinline__ void xcd_swz(int& bx, int& by, int& bz) {
  const int gx = gridDim.x, gy = gridDim.y;
  const int nwg = gx * gy * (int)gridDim.z;
  const int flat = blockIdx.x + gx * (blockIdx.y + gy * blockIdx.z);
  const int q = nwg >> 3;
  const int nf = (flat & 7) * q + (flat >> 3);
  bx = nf % gx;
  const int r = nf / gx;
  by = r % gy;
  bz = r / gy;
}

// ---- fused prep: 4x fp32->bf16 weight conversion + bias concat, one dispatch ----
// wout = contiguous [wq|wk|wv|wo] bf16 region (4 x 262144).
__global__ __launch_bounds__(256) void prep(const float* __restrict__ wq,
                                            const float* __restrict__ wk,
                                            const float* __restrict__ wv,
                                            const float* __restrict__ wo,
                                            const float* __restrict__ bq,
                                            const float* __restrict__ bk,
                                            u16* __restrict__ wout,
                                            float* __restrict__ bqk) {
  const int bid = blockIdx.x;
  const int tid = threadIdx.x;
  if (bid < 4096) {
    const int i = bid * 256 + tid;          // 0..1048575
    const int sel = i >> 18;                // which weight matrix
    const int off = i & 262143;
    const float* src = (sel == 0) ? wq : (sel == 1) ? wk : (sel == 2) ? wv : wo;
    wout[i] = f2bf(src[off]);
  } else {
    const int i = (bid - 4096) * 256 + tid; // 0..1023
    bqk[i] = (i < 512) ? bq[i] : bk[i - 512];
  }
}

// ---------------- softmax denominator: Lr[b,i] = 1/sum_jb partial ----------------
__global__ __launch_bounds__(256) void reduce_l(const float* __restrict__ p,
                                                float* __restrict__ lr) {
  const int i = blockIdx.x * 256 + threadIdx.x;   // 16384 = B*S
  const int b = i >> 12, row = i & 4095;
  float s = 0.f;
#pragma unroll
  for (int jb = 0; jb < 16; ++jb) s += p[((size_t)(b * 16 + jb) << 12) + row];
  lr[i] = 1.f / s;
}

// ------- GroupNorm stats, BW-saturating 2-stage (2048 blocks -> 1 block) -------
// stage 1: block blk reduces one contiguous 4096-float slice (16 KB); a (b,g)
// group = 16 consecutive slices. 2048 blocks = 8/CU -> full TLP, near-peak HBM.
__global__ __launch_bounds__(256) void gn_stats_part(const float* __restrict__ x,
                                                     float* __restrict__ part) {
  const int blk = blockIdx.x;               // 0..2047
  const float4* p4 = (const float4*)(x + (size_t)blk * 4096);
  float s = 0.f, ss = 0.f;
  const int tid = threadIdx.x;
#pragma unroll
  for (int i = 0; i < 4; ++i) {
    const float4 v = p4[tid + i * 256];
    s  += v.x + v.y + v.z + v.w;
    ss += v.x * v.x + v.y * v.y + v.z * v.z + v.w * v.w;
  }
#pragma unroll
  for (int o = 32; o; o >>= 1) { s += __shfl_xor(s, o, 64); ss += __shfl_xor(ss, o, 64); }
  __shared__ float sm[8];
  const int wid = tid >> 6, lane = tid & 63;
  if (lane == 0) { sm[wid * 2] = s; sm[wid * 2 + 1] = ss; }
  __syncthreads();
  if (tid == 0) {
    part[blk * 2]     = sm[0] + sm[2] + sm[4] + sm[6];
    part[blk * 2 + 1] = sm[1] + sm[3] + sm[5] + sm[7];
  }
}

// stage 2: one block, thread g finalizes group g from its 16 partials (deterministic)
__global__ __launch_bounds__(128) void gn_stats_fin(const float* __restrict__ part,
                                                    float* __restrict__ stats) {
  const int g = threadIdx.x;  // 0..127 = b*G_+grp
  float s = 0.f, ss = 0.f;
#pragma unroll
  for (int i = 0; i < 16; ++i) {
    s  += part[(g * 16 + i) * 2];
    ss += part[(g * 16 + i) * 2 + 1];
  }
  const float inv = 1.f / (float)(CPG_ * S_);
  const float mu = s * inv;
  const float var = ss * inv - mu * mu;
  stats[g * 2]     = mu;
  stats[g * 2 + 1] = rsqrtf(var + EPS_);
}

// ---------------- normalize + transpose: x[b,c,s] -> ht[b*s, c] bf16 ----------------
__global__ __launch_bounds__(256) void gn_apply_t(const float* __restrict__ x,
                                                  const float* __restrict__ gamma,
                                                  const float* __restrict__ beta,
                                                  const float* __restrict__ stats,
                                                  u16* __restrict__ ht) {
  __shared__ float tile[32][33];
  const int b = blockIdx.z, c0 = blockIdx.y * 32, s0 = blockIdx.x * 32;
  const int tx = threadIdx.x, ty = threadIdx.y;
#pragma unroll
  for (int i = 0; i < 4; ++i) {
    const int c  = c0 + ty + i * 8;
    const float mu = stats[(b * G_ + (c >> 4)) * 2];
    const float rs = stats[(b * G_ + (c >> 4)) * 2 + 1];
    const float v  = x[((size_t)b * C_ + c) * S_ + s0 + tx];
    tile[ty + i * 8][tx] = (v - mu) * rs * gamma[c] + beta[c];
  }
  __syncthreads();
#pragma unroll
  for (int i = 0; i < 4; ++i) {
    const int s = s0 + ty + i * 8;
    ht[((size_t)b * S_ + s) * C_ + c0 + tx] = f2bf(tile[tx][ty + i * 8]);
  }
}

// ======= 256x256 8-phase GEMM — single barrier/phase, compiler-counted lgkm =======
// C[m,n] = alpha * sum_k A[m,k]*B[n,k] (+bias[n]); A,B bf16 K-contiguous.
// 512 thr = 8 waves (2M x 4N), strided frags: m-frag f at wm+f*32, n-frag g at
// wn+g*64. LDS As/Bs[2 dbuf][2 half][128][64] u16; swizzle phys granule = g^(row&7).
// Phase = {ds_reads; stage; [counted vmcnt]; BAR; setprio(1) MFMA setprio(0)}.
// NO hard lgkmcnt(0): compiler emits per-fragment counted lgkm waits so MFMA
// starts as soon as its first frags land, and next phase's reads/stages issue
// under the MFMA tail. Counted vmcnt(4) at p3/p7 pre-barrier (asm volatile,
// unhoistable) drains exactly the 8 loads of the dbuf read next; steady state
// 12 loads in flight, never 0.
// ZMODE 1 = PV split-K: bz -> (b = bz>>1, kh = bz&1), hardcoded offsets.
// SMAX 1 = scores epilogue: write exp(alpha*acc) bf16 + per-block row-sum partials.
template <int BIAS_MODE, int ZMODE, int SMAX>
__global__ __launch_bounds__(512, 2) void gemm8p(
    const u16* __restrict__ Ag, int lda, long sA,
    const u16* __restrict__ Bg, int ldb, long sB,
    u16* __restrict__ Cg, int ldc, long sC,
    const float* __restrict__ bias, float alpha, int K,
    float* __restrict__ smx) {
  __shared__ u16 As[2][2][8192];
  __shared__ u16 Bs[2][2][8192];
  __shared__ float ps[4][256];
  int bx, by, bz;
  xcd_swz(bx, by, bz);
  const u16 *A, *Bm;
  u16* Cb;
  if (ZMODE == 0) {
    A = Ag + (size_t)bz * sA; Bm = Bg + (size_t)bz * sB; Cb = Cg + (size_t)bz * sC;
  } else {  // PV split-K: A = P[b], cols kh*2048+; B = V rows, cols b*4096+kh*2048+
    const int b = bz >> 1, kh = bz & 1;
    A  = Ag + (size_t)b * 16777216 + (size_t)kh * 2048;
    Bm = Bg + (size_t)b * 4096 + (size_t)kh * 2048;
    Cb = Cg + (size_t)kh * 8388608 + (size_t)b * 2097152;
  }
  const int bm = by * 256, bn = bx * 256;
  const int tid = threadIdx.x;
  const int wid = tid >> 6, lane = tid & 63;
  const int wm = (wid >> 2) * 16, wn = (wid & 3) * 16;
  const int lr = lane & 15, lh = lane >> 4;
  const int x7 = lr & 7;
  const int g0 = (lh ^ x7) * 8, g1 = ((4 | lh) ^ x7) * 8;  // swizzled granule offs (kh=0/1)

  // staging: wave w covers rows w*8..w*8+7 (+64) of each half; pre-swizzled source
  const int sg = (lane & 7) ^ ((lane >> 3) & 7);
  const u16* Abase = A  + (size_t)(bm + wid * 8 + (lane >> 3)) * lda + sg * 8;
  const u16* Bbase = Bm + (size_t)(bn + wid * 8 + (lane >> 3)) * ldb + sg * 8;

#define STGA(D, H, T) do {                                                   \
    const u16* _s = Abase + (size_t)((H) * 128) * lda + (size_t)(T) * 64;    \
    g2lds16(_s,                    &As[D][H][wid * 512]);                    \
    g2lds16(_s + (size_t)64 * lda, &As[D][H][4096 + wid * 512]);             \
  } while (0)
#define STGB(D, H, T) do {                                                   \
    const u16* _s = Bbase + (size_t)((H) * 128) * ldb + (size_t)(T) * 64;    \
    g2lds16(_s,                    &Bs[D][H][wid * 512]);                    \
    g2lds16(_s + (size_t)64 * ldb, &Bs[D][H][4096 + wid * 512]);             \
  } while (0)

  // bias preload FIRST: its 4 loads are oldest, drained by the prologue vmcnt(4)
  float bias_v[4] = {0.f, 0.f, 0.f, 0.f};
  if (BIAS_MODE == 1) {
#pragma unroll
    for (int g = 0; g < 4; ++g) bias_v[g] = bias[bn + wn + g * 64 + lr];
  }
  SCHED0();

  f32x4 acc[8][4];
  const f32x4 zero = {0.f, 0.f, 0.f, 0.f};
#pragma unroll
  for (int i = 0; i < 8; ++i)
#pragma unroll
    for (int j = 0; j < 4; ++j) acc[i][j] = zero;

  bf16x8 a_[4][2], b_[4][2];

#define RDA(D, AH) do {                                                      \
    _Pragma("unroll") for (int i = 0; i < 4; ++i) {                          \
      const int _o = (wm + i * 32 + lr) * 64;                                \
      a_[i][0] = *(const bf16x8*)&As[D][AH][_o + g0];                        \
      a_[i][1] = *(const bf16x8*)&As[D][AH][_o + g1];                        \
    } } while (0)
#define RDB(D, BH) do {                                                      \
    _Pragma("unroll") for (int j = 0; j < 2; ++j) {                          \
      const int _o = (wn + j * 64 + lr) * 64;                                \
      b_[(BH) * 2 + j][0] = *(const bf16x8*)&Bs[D][BH][_o + g0];             \
      b_[(BH) * 2 + j][1] = *(const bf16x8*)&Bs[D][BH][_o + g1];             \
    } } while (0)
#define MM(AH, BH) do {                                                      \
    __builtin_amdgcn_s_setprio(1);                                           \
    _Pragma("unroll") for (int i = 0; i < 4; ++i)                            \
    _Pragma("unroll") for (int j = 0; j < 2; ++j) {                          \
      acc[(AH) * 4 + i][(BH) * 2 + j] = __builtin_amdgcn_mfma_f32_16x16x32_bf16( \
          a_[i][0], b_[(BH) * 2 + j][0], acc[(AH) * 4 + i][(BH) * 2 + j], 0, 0, 0); \
      acc[(AH) * 4 + i][(BH) * 2 + j] = __builtin_amdgcn_mfma_f32_16x16x32_bf16( \
          a_[i][1], b_[(BH) * 2 + j][1], acc[(AH) * 4 + i][(BH) * 2 + j], 0, 0, 0); \
    }                                                                        \
    __builtin_amdgcn_s_setprio(0);                                           \
  } while (0)

  // prologue: tile0 all 4 halves, then tile1 A0,B1; drain tile0 BEFORE the barrier
  STGA(0, 0, 0); STGB(0, 1, 0); STGA(0, 1, 0); STGB(0, 0, 0);
  STGA(1, 0, 1); STGB(1, 1, 1);
  WAITV4;
  BAR();

  const int nt = K >> 6;  // even, >= 4
  for (int i = 0; i < nt / 2; ++i) {
    const int t1 = 2 * i + 1, t2 = 2 * i + 2, t3 = 2 * i + 3;
    const bool s2 = t2 < nt, s3 = t3 < nt;
    // p0 (d0, A0,B0)
    RDA(0, 0); RDB(0, 0);
    STGB(1, 0, t1);
    BAR(); MM(0, 0);
    // p1 (d0, A0,B1)
    RDB(0, 1);
    STGA(1, 1, t1);
    BAR(); MM(0, 1);
    // p2 (d0, A1,B1)
    RDA(0, 1);
    if (s2) STGA(0, 0, t2);
    BAR(); MM(1, 1);
    // p3 (d0, A1,B0) — counted drain of d1's stages before the phase barrier
    if (s2) STGB(0, 1, t2);
    if (s2) { WAITV4; } else { WAITV0; }
    BAR(); MM(1, 0);
    // p4 (d1, A0,B0)
    RDA(1, 0); RDB(1, 0);
    if (s2) STGA(0, 1, t2);
    BAR(); MM(0, 0);
    // p5 (d1, A0,B1)
    RDB(1, 1);
    if (s2) STGB(0, 0, t2);
    BAR(); MM(0, 1);
    // p6 (d1, A1,B1)
    RDA(1, 1);
    if (s3) STGA(1, 0, t3);
    BAR(); MM(1, 1);
    // p7 (d1, A1,B0) — counted drain of next d0's stages before the phase barrier
    if (s3) STGB(1, 1, t3);
    if (s3) { WAITV4; }
    BAR(); MM(1, 0);
  }
#undef STGA
#undef STGB
#undef RDA
#undef RDB
#undef MM
  SCHED0();

  if (SMAX) {
    // P = exp(alpha*s) bf16 + per-(row, col-block) partial sums -> smx
    float rs[8][4];
#pragma unroll
    for (int f = 0; f < 8; ++f) {
      const int row0 = bm + wm + f * 32 + lh * 4;
#pragma unroll
      for (int r = 0; r < 4; ++r) rs[f][r] = 0.f;
#pragma unroll
      for (int g = 0; g < 4; ++g) {
        const int col = bn + wn + g * 64 + lr;
#pragma unroll
        for (int r = 0; r < 4; ++r) {
          const float e = __expf(acc[f][g][r] * alpha);
          rs[f][r] += e;
          Cb[(size_t)(row0 + r) * ldc + col] = f2bf(e);
        }
      }
#pragma unroll
      for (int r = 0; r < 4; ++r) {
        float v = rs[f][r];
        v += __shfl_xor(v, 1, 64);
        v += __shfl_xor(v, 2, 64);
        v += __shfl_xor(v, 4, 64);
        v += __shfl_xor(v, 8, 64);
        rs[f][r] = v;
      }
    }
    // cross-wave (over wn) reduction: compile-time-predicated LDS writes
#pragma unroll
    for (int f = 0; f < 8; ++f)
#pragma unroll
      for (int r = 0; r < 4; ++r)
        if (lr == ((f << 1) | (r >> 1)))
          ps[wid & 3][wm + f * 32 + lh * 4 + r] = rs[f][r];
    __syncthreads();
    if (tid < 256) {
      const float tot = ps[0][tid] + ps[1][tid] + ps[2][tid] + ps[3][tid];
      smx[((size_t)(bz * 16 + bx) << 12) + bm + tid] = tot;
    }
  } else {
#pragma unroll
    for (int f = 0; f < 8; ++f) {
      const int row0 = bm + wm + f * 32 + lh * 4;
#pragma unroll
      for (int g = 0; g < 4; ++g) {
        const int col = bn + wn + g * 64 + lr;
#pragma unroll
        for (int r = 0; r < 4; ++r)
          Cb[(size_t)(row0 + r) * ldc + col] = f2bf(acc[f][g][r] * alpha + bias_v[g]);
      }
    }
  }
}

// ---------------- 128x128 GEMM (V-proj and out-proj) ----------------
// BCOMB=1: B-operand is the fp32 sum of two bf16 psum buffers (Bg, Bg2), added
// during reg-staged B-staging (replaces the separate add_scale pass).
// OUT_MODE=1: fp32 out[b,o,s] = acc*lscale[n] + bias[m] + xres, n = b*S+s.
#define GBM 128
#define GBN 128
#define GBK 64

template <int BIAS_MODE, int OUT_MODE, int BCOMB>
__global__ __launch_bounds__(256) void gemm_abT(
    const u16* __restrict__ Ag, int lda, long sA,
    const u16* __restrict__ Bg, int ldb, long sB,
    void* __restrict__ Cg, int ldc, long sC,
    const float* __restrict__ bias, float alpha,
    const float* __restrict__ xres, const float* __restrict__ lscale,
    const u16* __restrict__ Bg2, int K) {
  __shared__ u16 As[GBM * GBK];
  __shared__ u16 Bs[GBN * GBK];
  const int bz = blockIdx.z;
  const u16* A    = Ag + (size_t)bz * sA;
  const u16* Bmat = Bg + (size_t)bz * sB;
  const int bm = blockIdx.y * GBM, bn = blockIdx.x * GBN;
  const int tid = threadIdx.x;
  const int wid = tid >> 6, lane = tid & 63;
  const int wm = (wid >> 1) * 64, wn = (wid & 1) * 64;
  const int lr = lane & 15, lh = lane >> 4;
  const int srow = lane >> 3, scol = (lane & 7) * 8;

  f32x4 acc[4][4];
  const f32x4 zero = {0.f, 0.f, 0.f, 0.f};
#pragma unroll
  for (int i = 0; i < 4; ++i)
#pragma unroll
    for (int j = 0; j < 4; ++j) acc[i][j] = zero;

  for (int k0 = 0; k0 < K; k0 += GBK) {
    __syncthreads();
#pragma unroll
    for (int i = 0; i < 4; ++i) {
      const int chunk = wid * 4 + i;
      const int row   = chunk * 8 + srow;
      g2lds16(A + (size_t)(bm + row) * lda + (k0 + scol), &As[chunk * 512]);
      if (BCOMB == 0) {
        g2lds16(Bmat + (size_t)(bn + row) * ldb + (k0 + scol), &Bs[chunk * 512]);
      } else {
        const size_t boff = (size_t)(bn + row) * ldb + (k0 + scol);
        const uint4 u0 = *(const uint4*)(Bmat + boff);
        const uint4 u1 = *(const uint4*)(Bg2 + boff);
        const unsigned* p0 = (const unsigned*)&u0;
        const unsigned* p1 = (const unsigned*)&u1;
        unsigned rr[4];
#pragma unroll
        for (int k = 0; k < 4; ++k) {
          const float lo = bf2f((u16)(p0[k] & 0xffffu)) + bf2f((u16)(p1[k] & 0xffffu));
          const float hi = bf2f((u16)(p0[k] >> 16)) + bf2f((u16)(p1[k] >> 16));
          rr[k] = (unsigned)f2bf(lo) | ((unsigned)f2bf(hi) << 16);
        }
        *(uint4*)&Bs[chunk * 512 + lane * 8] = *(const uint4*)rr;
      }
    }
    __syncthreads();
#pragma unroll
    for (int ks = 0; ks < 2; ++ks) {
      bf16x8 a_[4], b_[4];
#pragma unroll
      for (int m = 0; m < 4; ++m)
        a_[m] = *(const bf16x8*)&As[(wm + m * 16 + lr) * GBK + ks * 32 + lh * 8];
#pragma unroll
      for (int n = 0; n < 4; ++n)
        b_[n] = *(const bf16x8*)&Bs[(wn + n * 16 + lr) * GBK + ks * 32 + lh * 8];
#pragma unroll
      for (int m = 0; m < 4; ++m)
#pragma unroll
        for (int n = 0; n < 4; ++n)
          acc[m][n] = __builtin_amdgcn_mfma_f32_16x16x32_bf16(a_[m], b_[n], acc[m][n], 0, 0, 0);
    }
  }

  if (OUT_MODE == 0) {
    u16* Cb = (u16*)Cg + (size_t)bz * sC;
#pragma unroll
    for (int m = 0; m < 4; ++m) {
      const int row0 = bm + wm + m * 16 + lh * 4;
#pragma unroll
      for (int n = 0; n < 4; ++n) {
        const int col = bn + wn + n * 16 + lr;
        float bn_ = (BIAS_MODE == 1) ? bias[col] : 0.f;
#pragma unroll
        for (int r = 0; r < 4; ++r) {
          float bb = (BIAS_MODE == 2) ? bias[row0 + r] : bn_;
          Cb[(size_t)(row0 + r) * ldc + col] = f2bf(acc[m][n][r] * alpha + bb);
        }
      }
    }
  } else {
    float* Ob = (float*)Cg;
#pragma unroll
    for (int m = 0; m < 4; ++m) {
      const int row0 = bm + wm + m * 16 + lh * 4;
#pragma unroll
      for (int n = 0; n < 4; ++n) {
        const int col = bn + wn + n * 16 + lr;
        const int bb = col >> 12, sp = col & (S_ - 1);
        const float lsc = lscale[col];
#pragma unroll
        for (int r = 0; r < 4; ++r) {
          const int o = row0 + r;
          const size_t idx = ((size_t)bb * C_ + o) * S_ + sp;
          Ob[idx] = acc[m][n][r] * lsc + bias[o] + xres[idx];
        }
      }
    }
  }
}

extern "C" void kernel_launch(void* const* d_in, const int* in_sizes, int n_in,
                              void* d_out, int out_size, void* d_ws, size_t ws_size,
                              hipStream_t stream) {
  const float* x     = (const float*)d_in[0];
  const float* gamma = (const float*)d_in[1];
  const float* beta  = (const float*)d_in[2];
  const float* wq = (const float*)d_in[3];
  const float* bq = (const float*)d_in[4];
  const float* wk = (const float*)d_in[5];
  const float* bk = (const float*)d_in[6];
  const float* wv = (const float*)d_in[7];
  const float* bv = (const float*)d_in[8];
  const float* wo = (const float*)d_in[9];
  const float* bo = (const float*)d_in[10];
  float* out = (float*)d_out;

  // ws: stats 1KB | weights bf16 4x512KB | bqk 4KB | ht 16MB | qkt 32MB | vv 16MB
  //     | sc 128MB | partials 1MB | Lr 64KB | gn part 16KB
  char* ws = (char*)d_ws;
  float* stats = (float*)ws;
  u16* wqb = (u16*)(ws + 1024);
  u16* wkb = wqb + 262144;   // contiguous after wqb -> [wq;wk] is one 1024x512 matrix
  u16* wvb = wkb + 262144;
  u16* wob = wvb + 262144;
  float* bqk = (float*)(wob + 262144);
  u16* ht  = (u16*)((char*)bqk + 4096);  // [B*S, C]
  u16* qkt = ht + 8388608;               // [B*S, 1024] (q|k); later PV psum halves
  u16* vv  = qkt + 16777216;             // [C, B*S]
  u16* sc  = vv + 8388608;               // [B, S, S] exp(scores)
  float* partials = (float*)(sc + 67108864);  // [B][16][4096]
  float* Lr = partials + 262144;              // [B][4096]
  float* gnp = Lr + 16384;                    // [2048][2] gn stats partials

  // fused weight-convert + bias-concat (replaces 5 tiny dispatches)
  prep<<<4100, 256, 0, stream>>>(wq, wk, wv, wo, bq, bk, wqb, bqk);

  gn_stats_part<<<2048, 256, 0, stream>>>(x, gnp);
  gn_stats_fin<<<1, 128, 0, stream>>>(gnp, stats);
  gn_apply_t<<<dim3(128, 16, 4), dim3(32, 8), 0, stream>>>(x, gamma, beta, stats, ht);

  // fused Q|K projection: qkt[bs, 0:512]=Q, [512:1024]=K   (256 blocks)
  gemm8p<1, 0, 0><<<dim3(4, 64, 1), 512, 0, stream>>>(ht, 512, 0, wqb, 512, 0,
                                                      qkt, 1024, 0, bqk, 1.f, 512, nullptr);
  // V[c, b*S+s]: bias per m (=c)                            (512 blocks)
  gemm_abT<2, 0, 0><<<dim3(128, 4, 1), 256, 0, stream>>>(wvb, 512, 0, ht, 512, 0,
                                                         vv, 16384, 0, bv, 1.f,
                                                         nullptr, nullptr, nullptr, 512);
  // P[b,i,j] = exp(scale * Q.K) + row-sum partials          (1024 blocks)
  gemm8p<0, 0, 1><<<dim3(16, 16, 4), 512, 0, stream>>>(qkt, 1024, 4194304, qkt + 512, 1024, 4194304,
                                                       sc, 4096, 16777216, nullptr,
                                                       0.04419417382415922f, 512, partials);
  reduce_l<<<64, 256, 0, stream>>>(partials, Lr);
  // PV split-K=2 on unnormalized P: psums in qkt halves     (256 blocks)
  gemm8p<0, 1, 0><<<dim3(2, 16, 8), 512, 0, stream>>>(sc, 4096, 0, vv, 16384, 0,
                                                      qkt, 512, 0, nullptr, 1.f, 2048, nullptr);
  // out[b,o,s] = (Wo @ (psum0+psum1)) * Lr[bs] + bo + x      (512 blocks)
  gemm_abT<2, 1, 1><<<dim3(128, 4, 1), 256, 0, stream>>>(wob, 512, 0, qkt, 512, 0,
                                                         out, 0, 0, bo, 1.f,
                                                         x, Lr, qkt + 8388608, 512);
}

// Round 19
// 262.502 us; speedup vs baseline: 1.2479x; 1.0232x over previous
//
#include <hip/hip_runtime.h>

#define B_   4
#define C_   512
#define S_   4096
#define G_   32
#define CPG_ 16
#define EPS_ 1e-6f

typedef unsigned short u16;
typedef __bf16 bf16x8 __attribute__((ext_vector_type(8)));
typedef float  f32x4  __attribute__((ext_vector_type(4)));

__device__ __forceinline__ u16 f2bf(float f) {
  unsigned u = __float_as_uint(f);
  u += 0x7fffu + ((u >> 16) & 1u);   // RNE
  return (u16)(u >> 16);
}
__device__ __forceinline__ float bf2f(u16 h) {
  return __uint_as_float((unsigned)h << 16);
}

__device__ __forceinline__ void g2lds16(const void* g, void* l) {
  __builtin_amdgcn_global_load_lds(
      (const __attribute__((address_space(1))) void*)g,
      (__attribute__((address_space(3))) void*)l, 16, 0, 0);
}

#define BAR()    __builtin_amdgcn_s_barrier()
#define SCHED0() __builtin_amdgcn_sched_barrier(0)
#define WAITV4   asm volatile("s_waitcnt vmcnt(4)" ::: "memory")
#define WAITV0   asm volatile("s_waitcnt vmcnt(0)" ::: "memory")

// chunked XCD swizzle (bijective when nwg % 8 == 0 — all grids here satisfy it)
__device__ __forceinline__ void xcd_swz(int& bx, int& by, int& bz) {
  const int gx = gridDim.x, gy = gridDim.y;
  const int nwg = gx * gy * (int)gridDim.z;
  const int flat = blockIdx.x + gx * (blockIdx.y + gy * blockIdx.z);
  const int q = nwg >> 3;
  const int nf = (flat & 7) * q + (flat >> 3);
  bx = nf % gx;
  const int r = nf / gx;
  by = r % gy;
  bz = r / gy;
}

// ---- fused prep: 4x fp32->bf16 weight conversion + bias concat, one dispatch ----
// wout = contiguous [wq|wk|wv|wo] bf16 region (4 x 262144).
__global__ __launch_bounds__(256) void prep(const float* __restrict__ wq,
                                            const float* __restrict__ wk,
                                            const float* __restrict__ wv,
                                            const float* __restrict__ wo,
                                            const float* __restrict__ bq,
                                            const float* __restrict__ bk,
                                            u16* __restrict__ wout,
                                            float* __restrict__ bqk) {
  const int bid = blockIdx.x;
  const int tid = threadIdx.x;
  if (bid < 4096) {
    const int i = bid * 256 + tid;          // 0..1048575
    const int sel = i >> 18;                // which weight matrix
    const int off = i & 262143;
    const float* src = (sel == 0) ? wq : (sel == 1) ? wk : (sel == 2) ? wv : wo;
    wout[i] = f2bf(src[off]);
  } else {
    const int i = (bid - 4096) * 256 + tid; // 0..1023
    bqk[i] = (i < 512) ? bq[i] : bk[i - 512];
  }
}

// ---------------- softmax denominator: Lr[b,i] = 1/sum_jb partial ----------------
__global__ __launch_bounds__(256) void reduce_l(const float* __restrict__ p,
                                                float* __restrict__ lr) {
  const int i = blockIdx.x * 256 + threadIdx.x;   // 16384 = B*S
  const int b = i >> 12, row = i & 4095;
  float s = 0.f;
#pragma unroll
  for (int jb = 0; jb < 16; ++jb) s += p[((size_t)(b * 16 + jb) << 12) + row];
  lr[i] = 1.f / s;
}

// ------- GroupNorm stats, BW-saturating 2-stage (2048 blocks -> 1 block) -------
__global__ __launch_bounds__(256) void gn_stats_part(const float* __restrict__ x,
                                                     float* __restrict__ part) {
  const int blk = blockIdx.x;               // 0..2047
  const float4* p4 = (const float4*)(x + (size_t)blk * 4096);
  float s = 0.f, ss = 0.f;
  const int tid = threadIdx.x;
#pragma unroll
  for (int i = 0; i < 4; ++i) {
    const float4 v = p4[tid + i * 256];
    s  += v.x + v.y + v.z + v.w;
    ss += v.x * v.x + v.y * v.y + v.z * v.z + v.w * v.w;
  }
#pragma unroll
  for (int o = 32; o; o >>= 1) { s += __shfl_xor(s, o, 64); ss += __shfl_xor(ss, o, 64); }
  __shared__ float sm[8];
  const int wid = tid >> 6, lane = tid & 63;
  if (lane == 0) { sm[wid * 2] = s; sm[wid * 2 + 1] = ss; }
  __syncthreads();
  if (tid == 0) {
    part[blk * 2]     = sm[0] + sm[2] + sm[4] + sm[6];
    part[blk * 2 + 1] = sm[1] + sm[3] + sm[5] + sm[7];
  }
}

// stage 2: one block, thread g finalizes group g from its 16 partials (deterministic)
__global__ __launch_bounds__(128) void gn_stats_fin(const float* __restrict__ part,
                                                    float* __restrict__ stats) {
  const int g = threadIdx.x;  // 0..127 = b*G_+grp
  float s = 0.f, ss = 0.f;
#pragma unroll
  for (int i = 0; i < 16; ++i) {
    s  += part[(g * 16 + i) * 2];
    ss += part[(g * 16 + i) * 2 + 1];
  }
  const float inv = 1.f / (float)(CPG_ * S_);
  const float mu = s * inv;
  const float var = ss * inv - mu * mu;
  stats[g * 2]     = mu;
  stats[g * 2 + 1] = rsqrtf(var + EPS_);
}

// ---- normalize + transpose, vectorized: x[b,c,s] -> ht[b*s, c] bf16 ----
// 64(c) x 64(s) tile per block, 2048 blocks. float4 reads (16B/lane), LDS
// [64][65] fp32 staging (both phases ~2-way banks = free), short4 writes
// (8B/lane, 128B per 16-lane segment). Math identical to the scalar version.
__global__ __launch_bounds__(256) void gn_apply_t(const float* __restrict__ x,
                                                  const float* __restrict__ gamma,
                                                  const float* __restrict__ beta,
                                                  const float* __restrict__ stats,
                                                  u16* __restrict__ ht) {
  __shared__ float tile[64][65];
  const int b = blockIdx.z, c0 = blockIdx.y * 64, s0 = blockIdx.x * 64;
  const int tid = threadIdx.x;
  const int tq = tid >> 4, tr = tid & 15;   // 16 groups x 16 lanes
#pragma unroll
  for (int i = 0; i < 4; ++i) {
    const int cl = i * 16 + tq;             // local c row
    const int c  = c0 + cl;
    const float mu = stats[(b * G_ + (c >> 4)) * 2];
    const float rs = stats[(b * G_ + (c >> 4)) * 2 + 1];
    const float ga = gamma[c], be = beta[c];
    const float4 v = *(const float4*)&x[((size_t)b * C_ + c) * S_ + s0 + tr * 4];
    tile[cl][tr * 4 + 0] = (v.x - mu) * rs * ga + be;
    tile[cl][tr * 4 + 1] = (v.y - mu) * rs * ga + be;
    tile[cl][tr * 4 + 2] = (v.z - mu) * rs * ga + be;
    tile[cl][tr * 4 + 3] = (v.w - mu) * rs * ga + be;
  }
  __syncthreads();
#pragma unroll
  for (int i = 0; i < 4; ++i) {
    const int sl = i * 16 + tq;             // local s row
    const int cl = tr * 4;                  // local c (4 consecutive)
    u16 o[4];
#pragma unroll
    for (int j = 0; j < 4; ++j) o[j] = f2bf(tile[cl + j][sl]);
    *(uint2*)&ht[((size_t)b * S_ + s0 + sl) * C_ + c0 + cl] = *(const uint2*)o;
  }
}

// ======= 256x256 8-phase GEMM — single barrier/phase, compiler-counted lgkm =======
// C[m,n] = alpha * sum_k A[m,k]*B[n,k] (+bias[n]); A,B bf16 K-contiguous.
// 512 thr = 8 waves (2M x 4N), strided frags: m-frag f at wm+f*32, n-frag g at
// wn+g*64. LDS As/Bs[2 dbuf][2 half][128][64] u16; swizzle phys granule = g^(row&7).
// Phase = {ds_reads; stage; [counted vmcnt]; BAR; setprio(1) MFMA setprio(0)}.
// NO hard lgkmcnt(0): compiler emits per-fragment counted lgkm waits so MFMA
// starts as soon as its first frags land, and next phase's reads/stages issue
// under the MFMA tail. Counted vmcnt(4) at p3/p7 pre-barrier (asm volatile,
// unhoistable) drains exactly the 8 loads of the dbuf read next; steady state
// 12 loads in flight, never 0.
// ZMODE 1 = PV split-K: bz -> (b = bz>>1, kh = bz&1), hardcoded offsets.
// SMAX 1 = scores epilogue: write exp(alpha*acc) bf16 + per-block row-sum partials.
template <int BIAS_MODE, int ZMODE, int SMAX>
__global__ __launch_bounds__(512, 2) void gemm8p(
    const u16* __restrict__ Ag, int lda, long sA,
    const u16* __restrict__ Bg, int ldb, long sB,
    u16* __restrict__ Cg, int ldc, long sC,
    const float* __restrict__ bias, float alpha, int K,
    float* __restrict__ smx) {
  __shared__ u16 As[2][2][8192];
  __shared__ u16 Bs[2][2][8192];
  __shared__ float ps[4][256];
  int bx, by, bz;
  xcd_swz(bx, by, bz);
  const u16 *A, *Bm;
  u16* Cb;
  if (ZMODE == 0) {
    A = Ag + (size_t)bz * sA; Bm = Bg + (size_t)bz * sB; Cb = Cg + (size_t)bz * sC;
  } else {  // PV split-K: A = P[b], cols kh*2048+; B = V rows, cols b*4096+kh*2048+
    const int b = bz >> 1, kh = bz & 1;
    A  = Ag + (size_t)b * 16777216 + (size_t)kh * 2048;
    Bm = Bg + (size_t)b * 4096 + (size_t)kh * 2048;
    Cb = Cg + (size_t)kh * 8388608 + (size_t)b * 2097152;
  }
  const int bm = by * 256, bn = bx * 256;
  const int tid = threadIdx.x;
  const int wid = tid >> 6, lane = tid & 63;
  const int wm = (wid >> 2) * 16, wn = (wid & 3) * 16;
  const int lr = lane & 15, lh = lane >> 4;
  const int x7 = lr & 7;
  const int g0 = (lh ^ x7) * 8, g1 = ((4 | lh) ^ x7) * 8;  // swizzled granule offs (kh=0/1)

  // staging: wave w covers rows w*8..w*8+7 (+64) of each half; pre-swizzled source
  const int sg = (lane & 7) ^ ((lane >> 3) & 7);
  const u16* Abase = A  + (size_t)(bm + wid * 8 + (lane >> 3)) * lda + sg * 8;
  const u16* Bbase = Bm + (size_t)(bn + wid * 8 + (lane >> 3)) * ldb + sg * 8;

#define STGA(D, H, T) do {                                                   \
    const u16* _s = Abase + (size_t)((H) * 128) * lda + (size_t)(T) * 64;    \
    g2lds16(_s,                    &As[D][H][wid * 512]);                    \
    g2lds16(_s + (size_t)64 * lda, &As[D][H][4096 + wid * 512]);             \
  } while (0)
#define STGB(D, H, T) do {                                                   \
    const u16* _s = Bbase + (size_t)((H) * 128) * ldb + (size_t)(T) * 64;    \
    g2lds16(_s,                    &Bs[D][H][wid * 512]);                    \
    g2lds16(_s + (size_t)64 * ldb, &Bs[D][H][4096 + wid * 512]);             \
  } while (0)

  // bias preload FIRST: its 4 loads are oldest, drained by the prologue vmcnt(4)
  float bias_v[4] = {0.f, 0.f, 0.f, 0.f};
  if (BIAS_MODE == 1) {
#pragma unroll
    for (int g = 0; g < 4; ++g) bias_v[g] = bias[bn + wn + g * 64 + lr];
  }
  SCHED0();

  f32x4 acc[8][4];
  const f32x4 zero = {0.f, 0.f, 0.f, 0.f};
#pragma unroll
  for (int i = 0; i < 8; ++i)
#pragma unroll
    for (int j = 0; j < 4; ++j) acc[i][j] = zero;

  bf16x8 a_[4][2], b_[4][2];

#define RDA(D, AH) do {                                                      \
    _Pragma("unroll") for (int i = 0; i < 4; ++i) {                          \
      const int _o = (wm + i * 32 + lr) * 64;                                \
      a_[i][0] = *(const bf16x8*)&As[D][AH][_o + g0];                        \
      a_[i][1] = *(const bf16x8*)&As[D][AH][_o + g1];                        \
    } } while (0)
#define RDB(D, BH) do {                                                      \
    _Pragma("unroll") for (int j = 0; j < 2; ++j) {                          \
      const int _o = (wn + j * 64 + lr) * 64;                                \
      b_[(BH) * 2 + j][0] = *(const bf16x8*)&Bs[D][BH][_o + g0];             \
      b_[(BH) * 2 + j][1] = *(const bf16x8*)&Bs[D][BH][_o + g1];             \
    } } while (0)
#define MM(AH, BH) do {                                                      \
    __builtin_amdgcn_s_setprio(1);                                           \
    _Pragma("unroll") for (int i = 0; i < 4; ++i)                            \
    _Pragma("unroll") for (int j = 0; j < 2; ++j) {                          \
      acc[(AH) * 4 + i][(BH) * 2 + j] = __builtin_amdgcn_mfma_f32_16x16x32_bf16( \
          a_[i][0], b_[(BH) * 2 + j][0], acc[(AH) * 4 + i][(BH) * 2 + j], 0, 0, 0); \
      acc[(AH) * 4 + i][(BH) * 2 + j] = __builtin_amdgcn_mfma_f32_16x16x32_bf16( \
          a_[i][1], b_[(BH) * 2 + j][1], acc[(AH) * 4 + i][(BH) * 2 + j], 0, 0, 0); \
    }                                                                        \
    __builtin_amdgcn_s_setprio(0);                                           \
  } while (0)

  // prologue: tile0 all 4 halves, then tile1 A0,B1; drain tile0 BEFORE the barrier
  STGA(0, 0, 0); STGB(0, 1, 0); STGA(0, 1, 0); STGB(0, 0, 0);
  STGA(1, 0, 1); STGB(1, 1, 1);
  WAITV4;
  BAR();

  const int nt = K >> 6;  // even, >= 4
  for (int i = 0; i < nt / 2; ++i) {
    const int t1 = 2 * i + 1, t2 = 2 * i + 2, t3 = 2 * i + 3;
    const bool s2 = t2 < nt, s3 = t3 < nt;
    // p0 (d0, A0,B0)
    RDA(0, 0); RDB(0, 0);
    STGB(1, 0, t1);
    BAR(); MM(0, 0);
    // p1 (d0, A0,B1)
    RDB(0, 1);
    STGA(1, 1, t1);
    BAR(); MM(0, 1);
    // p2 (d0, A1,B1)
    RDA(0, 1);
    if (s2) STGA(0, 0, t2);
    BAR(); MM(1, 1);
    // p3 (d0, A1,B0) — counted drain of d1's stages before the phase barrier
    if (s2) STGB(0, 1, t2);
    if (s2) { WAITV4; } else { WAITV0; }
    BAR(); MM(1, 0);
    // p4 (d1, A0,B0)
    RDA(1, 0); RDB(1, 0);
    if (s2) STGA(0, 1, t2);
    BAR(); MM(0, 0);
    // p5 (d1, A0,B1)
    RDB(1, 1);
    if (s2) STGB(0, 0, t2);
    BAR(); MM(0, 1);
    // p6 (d1, A1,B1)
    RDA(1, 1);
    if (s3) STGA(1, 0, t3);
    BAR(); MM(1, 1);
    // p7 (d1, A1,B0) — counted drain of next d0's stages before the phase barrier
    if (s3) STGB(1, 1, t3);
    if (s3) { WAITV4; }
    BAR(); MM(1, 0);
  }
#undef STGA
#undef STGB
#undef RDA
#undef RDB
#undef MM
  SCHED0();

  if (SMAX) {
    // P = exp(alpha*s) bf16 + per-(row, col-block) partial sums -> smx
    float rs[8][4];
#pragma unroll
    for (int f = 0; f < 8; ++f) {
      const int row0 = bm + wm + f * 32 + lh * 4;
#pragma unroll
      for (int r = 0; r < 4; ++r) rs[f][r] = 0.f;
#pragma unroll
      for (int g = 0; g < 4; ++g) {
        const int col = bn + wn + g * 64 + lr;
#pragma unroll
        for (int r = 0; r < 4; ++r) {
          const float e = __expf(acc[f][g][r] * alpha);
          rs[f][r] += e;
          Cb[(size_t)(row0 + r) * ldc + col] = f2bf(e);
        }
      }
#pragma unroll
      for (int r = 0; r < 4; ++r) {
        float v = rs[f][r];
        v += __shfl_xor(v, 1, 64);
        v += __shfl_xor(v, 2, 64);
        v += __shfl_xor(v, 4, 64);
        v += __shfl_xor(v, 8, 64);
        rs[f][r] = v;
      }
    }
    // cross-wave (over wn) reduction: compile-time-predicated LDS writes
#pragma unroll
    for (int f = 0; f < 8; ++f)
#pragma unroll
      for (int r = 0; r < 4; ++r)
        if (lr == ((f << 1) | (r >> 1)))
          ps[wid & 3][wm + f * 32 + lh * 4 + r] = rs[f][r];
    __syncthreads();
    if (tid < 256) {
      const float tot = ps[0][tid] + ps[1][tid] + ps[2][tid] + ps[3][tid];
      smx[((size_t)(bz * 16 + bx) << 12) + bm + tid] = tot;
    }
  } else {
#pragma unroll
    for (int f = 0; f < 8; ++f) {
      const int row0 = bm + wm + f * 32 + lh * 4;
#pragma unroll
      for (int g = 0; g < 4; ++g) {
        const int col = bn + wn + g * 64 + lr;
#pragma unroll
        for (int r = 0; r < 4; ++r)
          Cb[(size_t)(row0 + r) * ldc + col] = f2bf(acc[f][g][r] * alpha + bias_v[g]);
      }
    }
  }
}

// ---------------- 128x128 GEMM (V-proj and out-proj) ----------------
// BCOMB=1: B-operand is the fp32 sum of two bf16 psum buffers (Bg, Bg2), added
// during reg-staged B-staging (replaces the separate add_scale pass).
// OUT_MODE=1: fp32 out[b,o,s] = acc*lscale[n] + bias[m] + xres, n = b*S+s.
#define GBM 128
#define GBN 128
#define GBK 64

template <int BIAS_MODE, int OUT_MODE, int BCOMB>
__global__ __launch_bounds__(256) void gemm_abT(
    const u16* __restrict__ Ag, int lda, long sA,
    const u16* __restrict__ Bg, int ldb, long sB,
    void* __restrict__ Cg, int ldc, long sC,
    const float* __restrict__ bias, float alpha,
    const float* __restrict__ xres, const float* __restrict__ lscale,
    const u16* __restrict__ Bg2, int K) {
  __shared__ u16 As[GBM * GBK];
  __shared__ u16 Bs[GBN * GBK];
  const int bz = blockIdx.z;
  const u16* A    = Ag + (size_t)bz * sA;
  const u16* Bmat = Bg + (size_t)bz * sB;
  const int bm = blockIdx.y * GBM, bn = blockIdx.x * GBN;
  const int tid = threadIdx.x;
  const int wid = tid >> 6, lane = tid & 63;
  const int wm = (wid >> 1) * 64, wn = (wid & 1) * 64;
  const int lr = lane & 15, lh = lane >> 4;
  const int srow = lane >> 3, scol = (lane & 7) * 8;

  f32x4 acc[4][4];
  const f32x4 zero = {0.f, 0.f, 0.f, 0.f};
#pragma unroll
  for (int i = 0; i < 4; ++i)
#pragma unroll
    for (int j = 0; j < 4; ++j) acc[i][j] = zero;

  for (int k0 = 0; k0 < K; k0 += GBK) {
    __syncthreads();
#pragma unroll
    for (int i = 0; i < 4; ++i) {
      const int chunk = wid * 4 + i;
      const int row   = chunk * 8 + srow;
      g2lds16(A + (size_t)(bm + row) * lda + (k0 + scol), &As[chunk * 512]);
      if (BCOMB == 0) {
        g2lds16(Bmat + (size_t)(bn + row) * ldb + (k0 + scol), &Bs[chunk * 512]);
      } else {
        const size_t boff = (size_t)(bn + row) * ldb + (k0 + scol);
        const uint4 u0 = *(const uint4*)(Bmat + boff);
        const uint4 u1 = *(const uint4*)(Bg2 + boff);
        const unsigned* p0 = (const unsigned*)&u0;
        const unsigned* p1 = (const unsigned*)&u1;
        unsigned rr[4];
#pragma unroll
        for (int k = 0; k < 4; ++k) {
          const float lo = bf2f((u16)(p0[k] & 0xffffu)) + bf2f((u16)(p1[k] & 0xffffu));
          const float hi = bf2f((u16)(p0[k] >> 16)) + bf2f((u16)(p1[k] >> 16));
          rr[k] = (unsigned)f2bf(lo) | ((unsigned)f2bf(hi) << 16);
        }
        *(uint4*)&Bs[chunk * 512 + lane * 8] = *(const uint4*)rr;
      }
    }
    __syncthreads();
#pragma unroll
    for (int ks = 0; ks < 2; ++ks) {
      bf16x8 a_[4], b_[4];
#pragma unroll
      for (int m = 0; m < 4; ++m)
        a_[m] = *(const bf16x8*)&As[(wm + m * 16 + lr) * GBK + ks * 32 + lh * 8];
#pragma unroll
      for (int n = 0; n < 4; ++n)
        b_[n] = *(const bf16x8*)&Bs[(wn + n * 16 + lr) * GBK + ks * 32 + lh * 8];
#pragma unroll
      for (int m = 0; m < 4; ++m)
#pragma unroll
        for (int n = 0; n < 4; ++n)
          acc[m][n] = __builtin_amdgcn_mfma_f32_16x16x32_bf16(a_[m], b_[n], acc[m][n], 0, 0, 0);
    }
  }

  if (OUT_MODE == 0) {
    u16* Cb = (u16*)Cg + (size_t)bz * sC;
#pragma unroll
    for (int m = 0; m < 4; ++m) {
      const int row0 = bm + wm + m * 16 + lh * 4;
#pragma unroll
      for (int n = 0; n < 4; ++n) {
        const int col = bn + wn + n * 16 + lr;
        float bn_ = (BIAS_MODE == 1) ? bias[col] : 0.f;
#pragma unroll
        for (int r = 0; r < 4; ++r) {
          float bb = (BIAS_MODE == 2) ? bias[row0 + r] : bn_;
          Cb[(size_t)(row0 + r) * ldc + col] = f2bf(acc[m][n][r] * alpha + bb);
        }
      }
    }
  } else {
    float* Ob = (float*)Cg;
#pragma unroll
    for (int m = 0; m < 4; ++m) {
      const int row0 = bm + wm + m * 16 + lh * 4;
#pragma unroll
      for (int n = 0; n < 4; ++n) {
        const int col = bn + wn + n * 16 + lr;
        const int bb = col >> 12, sp = col & (S_ - 1);
        const float lsc = lscale[col];
#pragma unroll
        for (int r = 0; r < 4; ++r) {
          const int o = row0 + r;
          const size_t idx = ((size_t)bb * C_ + o) * S_ + sp;
          Ob[idx] = acc[m][n][r] * lsc + bias[o] + xres[idx];
        }
      }
    }
  }
}

extern "C" void kernel_launch(void* const* d_in, const int* in_sizes, int n_in,
                              void* d_out, int out_size, void* d_ws, size_t ws_size,
                              hipStream_t stream) {
  const float* x     = (const float*)d_in[0];
  const float* gamma = (const float*)d_in[1];
  const float* beta  = (const float*)d_in[2];
  const float* wq = (const float*)d_in[3];
  const float* bq = (const float*)d_in[4];
  const float* wk = (const float*)d_in[5];
  const float* bk = (const float*)d_in[6];
  const float* wv = (const float*)d_in[7];
  const float* bv = (const float*)d_in[8];
  const float* wo = (const float*)d_in[9];
  const float* bo = (const float*)d_in[10];
  float* out = (float*)d_out;

  // ws: stats 1KB | weights bf16 4x512KB | bqk 4KB | ht 16MB | qkt 32MB | vv 16MB
  //     | sc 128MB | partials 1MB | Lr 64KB | gn part 16KB
  char* ws = (char*)d_ws;
  float* stats = (float*)ws;
  u16* wqb = (u16*)(ws + 1024);
  u16* wkb = wqb + 262144;   // contiguous after wqb -> [wq;wk] is one 1024x512 matrix
  u16* wvb = wkb + 262144;
  u16* wob = wvb + 262144;
  float* bqk = (float*)(wob + 262144);
  u16* ht  = (u16*)((char*)bqk + 4096);  // [B*S, C]
  u16* qkt = ht + 8388608;               // [B*S, 1024] (q|k); later PV psum halves
  u16* vv  = qkt + 16777216;             // [C, B*S]
  u16* sc  = vv + 8388608;               // [B, S, S] exp(scores)
  float* partials = (float*)(sc + 67108864);  // [B][16][4096]
  float* Lr = partials + 262144;              // [B][4096]
  float* gnp = Lr + 16384;                    // [2048][2] gn stats partials

  // fused weight-convert + bias-concat (replaces 5 tiny dispatches)
  prep<<<4100, 256, 0, stream>>>(wq, wk, wv, wo, bq, bk, wqb, bqk);

  gn_stats_part<<<2048, 256, 0, stream>>>(x, gnp);
  gn_stats_fin<<<1, 128, 0, stream>>>(gnp, stats);
  gn_apply_t<<<dim3(64, 8, 4), 256, 0, stream>>>(x, gamma, beta, stats, ht);

  // fused Q|K projection: qkt[bs, 0:512]=Q, [512:1024]=K   (256 blocks)
  gemm8p<1, 0, 0><<<dim3(4, 64, 1), 512, 0, stream>>>(ht, 512, 0, wqb, 512, 0,
                                                      qkt, 1024, 0, bqk, 1.f, 512, nullptr);
  // V[c, b*S+s]: bias per m (=c)                            (512 blocks)
  gemm_abT<2, 0, 0><<<dim3(128, 4, 1), 256, 0, stream>>>(wvb, 512, 0, ht, 512, 0,
                                                         vv, 16384, 0, bv, 1.f,
                                                         nullptr, nullptr, nullptr, 512);
  // P[b,i,j] = exp(scale * Q.K) + row-sum partials          (1024 blocks)
  gemm8p<0, 0, 1><<<dim3(16, 16, 4), 512, 0, stream>>>(qkt, 1024, 4194304, qkt + 512, 1024, 4194304,
                                                       sc, 4096, 16777216, nullptr,
                                                       0.04419417382415922f, 512, partials);
  reduce_l<<<64, 256, 0, stream>>>(partials, Lr);
  // PV split-K=2 on unnormalized P: psums in qkt halves     (256 blocks)
  gemm8p<0, 1, 0><<<dim3(2, 16, 8), 512, 0, stream>>>(sc, 4096, 0, vv, 16384, 0,
                                                      qkt, 512, 0, nullptr, 1.f, 2048, nullptr);
  // out[b,o,s] = (Wo @ (psum0+psum1)) * Lr[bs] + bo + x      (512 blocks)
  gemm_abT<2, 1, 1><<<dim3(128, 4, 1), 256, 0, stream>>>(wob, 512, 0, qkt, 512, 0,
                                                         out, 0, 0, bo, 1.f,
                                                         x, Lr, qkt + 8388608, 512);
}